// Round 7
// baseline (2187.205 us; speedup 1.0000x reference)
//
#include <hip/hip_runtime.h>

// RecurrentActorCritic B=512,T=512,S=64,H=128,A=8 (fp32 I/O).
// R6 post-mortem: FETCH/WRITE are KB (58/60 MB, not GB!) — HBM irrelevant.
// VGPR_Count pinned at 84 across 6 builds: compiler's immovable 6-waves/EU
// budget; our ~137-reg designs got weight REMATERIALIZATION (reload+cvt per
// step from L2) -> VALU/latency bloat. R7: design fits <=84.
//  Phase1: gx = Wih@relu(LN(x@Wf^T)) for all (b,t) -> d_ws as fp16 (201 MB).
//          half Wih row/thread (32 VGPR) + feature quarter-row (8 VGPR).
//  Phase2: sequential GRU, 1 chain/block, half Whh row/thread (32 VGPR),
//          shfl_xor(32) combine, gx streamed via 3-slot LDS ring.
// Fallback to the R6 single-kernel if ws_size < 201.3 MB.

typedef _Float16 h2t __attribute__((ext_vector_type(2)));
typedef float f16v __attribute__((ext_vector_type(16)));
typedef float f8v  __attribute__((ext_vector_type(8)));

__device__ __forceinline__ float dot2a(h2t a, h2t b, float c) {
    return __builtin_amdgcn_fdot2(a, b, c, false);
}
__device__ __forceinline__ h2t f2h(float f) { return __builtin_bit_cast(h2t, f); }
__device__ __forceinline__ float pk2(float lo, float hi) {
    h2t a; a.x = (_Float16)lo; a.y = (_Float16)hi;
    return __builtin_bit_cast(float, a);
}

#define BB 512
#define TT 512
#define SS 64
#define HH 128
#define AA 8
#define CH 128   // phase-1 time chunk

#define LDW16(WV, P2, OFS) { float2 v_; \
    v_=(P2)[(OFS)+0];  WV[0] =pk2(v_.x,v_.y); v_=(P2)[(OFS)+1];  WV[1] =pk2(v_.x,v_.y); \
    v_=(P2)[(OFS)+2];  WV[2] =pk2(v_.x,v_.y); v_=(P2)[(OFS)+3];  WV[3] =pk2(v_.x,v_.y); \
    v_=(P2)[(OFS)+4];  WV[4] =pk2(v_.x,v_.y); v_=(P2)[(OFS)+5];  WV[5] =pk2(v_.x,v_.y); \
    v_=(P2)[(OFS)+6];  WV[6] =pk2(v_.x,v_.y); v_=(P2)[(OFS)+7];  WV[7] =pk2(v_.x,v_.y); \
    v_=(P2)[(OFS)+8];  WV[8] =pk2(v_.x,v_.y); v_=(P2)[(OFS)+9];  WV[9] =pk2(v_.x,v_.y); \
    v_=(P2)[(OFS)+10]; WV[10]=pk2(v_.x,v_.y); v_=(P2)[(OFS)+11]; WV[11]=pk2(v_.x,v_.y); \
    v_=(P2)[(OFS)+12]; WV[12]=pk2(v_.x,v_.y); v_=(P2)[(OFS)+13]; WV[13]=pk2(v_.x,v_.y); \
    v_=(P2)[(OFS)+14]; WV[14]=pk2(v_.x,v_.y); v_=(P2)[(OFS)+15]; WV[15]=pk2(v_.x,v_.y); }

#define LDW8(WV, P2, OFS) { float2 v_; \
    v_=(P2)[(OFS)+0]; WV[0]=pk2(v_.x,v_.y); v_=(P2)[(OFS)+1]; WV[1]=pk2(v_.x,v_.y); \
    v_=(P2)[(OFS)+2]; WV[2]=pk2(v_.x,v_.y); v_=(P2)[(OFS)+3]; WV[3]=pk2(v_.x,v_.y); \
    v_=(P2)[(OFS)+4]; WV[4]=pk2(v_.x,v_.y); v_=(P2)[(OFS)+5]; WV[5]=pk2(v_.x,v_.y); \
    v_=(P2)[(OFS)+6]; WV[6]=pk2(v_.x,v_.y); v_=(P2)[(OFS)+7]; WV[7]=pk2(v_.x,v_.y); }

#define HDOT4(WV, J, U) \
    a0=dot2a(f2h(WV[(J)+0]),f2h(U.x),a0); a0=dot2a(f2h(WV[(J)+1]),f2h(U.y),a0); \
    a0=dot2a(f2h(WV[(J)+2]),f2h(U.z),a0); a0=dot2a(f2h(WV[(J)+3]),f2h(U.w),a0);

// half-row (32 pairs in w0,w1) dot LDS vector at ph4 (8 float4 = 64 elems)
#define HMV { float4 u_; \
    u_=ph4[0]; HDOT4(w0,0,u_)  u_=ph4[1]; HDOT4(w0,4,u_) \
    u_=ph4[2]; HDOT4(w0,8,u_)  u_=ph4[3]; HDOT4(w0,12,u_) \
    u_=ph4[4]; HDOT4(w1,0,u_)  u_=ph4[5]; HDOT4(w1,4,u_) \
    u_=ph4[6]; HDOT4(w1,8,u_)  u_=ph4[7]; HDOT4(w1,12,u_) }

#define FD4(WV, J, U) \
    f0=dot2a(f2h(WV[(J)+0]),f2h(U.x),f0); f1=dot2a(f2h(WV[(J)+1]),f2h(U.y),f1); \
    f0=dot2a(f2h(WV[(J)+2]),f2h(U.z),f0); f1=dot2a(f2h(WV[(J)+3]),f2h(U.w),f1);

// ======================= PHASE 1 =======================
__global__ void __launch_bounds__(768, 2) p1_kernel(
    const float* __restrict__ x,   const float* __restrict__ Wf,
    const float* __restrict__ bfe, const float* __restrict__ gf,
    const float* __restrict__ btf, const float* __restrict__ Wih,
    const float* __restrict__ bih, unsigned short* __restrict__ gxws)
{
    const int tid = threadIdx.x;
    const int b  = blockIdx.x >> 2;
    const int t0 = (blockIdx.x & 3) * CH;

    __shared__ __align__(16) _Float16 xh2[CH][SS];   // 16 KB chunk of x (fp16)
    __shared__ __align__(16) _Float16 zh[HH];
    __shared__ __align__(16) float fraw[HH];
    __shared__ float fred[8][2];

    const int l  = tid & 63;
    const int w  = tid >> 6;
    const int r  = (w << 5) | (l & 31);   // gate row 0..383
    const int hf = (l >> 5) & 1;          // which half of the row

    f16v w0, w1;   // half Wih row: 32 packed pairs
    {
        const float2* p2 = (const float2*)(Wih + r * HH + hf * 64);
        LDW16(w0, p2, 0) LDW16(w1, p2, 16)
    }
    const float breg = bih[r];

    f8v fw = {0.f,0.f,0.f,0.f,0.f,0.f,0.f,0.f};
    float bfr = 0.f;
    int fq = 0, fr = 0;
    if (tid >= 256) {                     // feature quarter-row
        int idx = tid - 256;
        fq = idx & 3; fr = idx >> 2;
        const float2* p2 = (const float2*)(Wf + fr * SS + fq * 16);
        LDW8(fw, p2, 0)
        bfr = bfe[fr];
    }
    float gfr = 0.f, btfr = 0.f;
    if (tid < HH) { gfr = gf[tid]; btfr = btf[tid]; }

    for (int idx = tid; idx < CH * SS; idx += 768) {
        int tl = idx >> 6, e = idx & 63;
        xh2[tl][e] = (_Float16)x[((size_t)b * TT + t0 + tl) * SS + e];
    }
    __syncthreads();

    for (int tt = 0; tt < CH; ++tt) {
        // SegA: feature dots (quarter-rows, combine over 4 lanes)
        if (tid >= 256) {
            const float4* px4 = ((const float4*)xh2[tt]) + fq * 2;
            float f0 = 0.f, f1 = 0.f;
            float4 u_;
            u_ = px4[0]; FD4(fw, 0, u_)
            u_ = px4[1]; FD4(fw, 4, u_)
            float p = f0 + f1;
            p += __shfl_xor(p, 1);
            p += __shfl_xor(p, 2);
            p += bfr;
            if (fq == 0) fraw[fr] = p;
            float s = p * 0.25f, q = p * p * 0.25f;  // each row appears on 4 lanes
            #pragma unroll
            for (int m = 1; m < 64; m <<= 1) { s += __shfl_xor(s, m); q += __shfl_xor(q, m); }
            if (l == 0) { fred[w - 4][0] = s; fred[w - 4][1] = q; }
        }
        __syncthreads();
        // SegB: LN + relu -> zh
        if (tid < HH) {
            float s = fred[0][0]+fred[1][0]+fred[2][0]+fred[3][0]
                    + fred[4][0]+fred[5][0]+fred[6][0]+fred[7][0];
            float q = fred[0][1]+fred[1][1]+fred[2][1]+fred[3][1]
                    + fred[4][1]+fred[5][1]+fred[6][1]+fred[7][1];
            float mu = s * (1.f / 128.f);
            float rstd = rsqrtf(q * (1.f / 128.f) - mu * mu + 1e-5f);
            float z = (fraw[tid] - mu) * rstd * gfr + btfr;
            zh[tid] = (_Float16)fmaxf(z, 0.f);
        }
        __syncthreads();
        // SegC: gx half-row matvec + fp16 store to ws
        {
            const float4* ph4 = ((const float4*)zh) + hf * 8;
            float a0 = 0.f;
            HMV
            a0 += __shfl_xor(a0, 32);
            if ((l & 32) == 0) {
                _Float16 g = (_Float16)(a0 + breg);
                gxws[((size_t)b * TT + t0 + tt) * 384 + r] =
                    __builtin_bit_cast(unsigned short, g);
            }
        }
    }
}

// ======================= PHASE 2 =======================
__global__ void __launch_bounds__(768, 2) p2_kernel(
    const float* __restrict__ hx,  const int* __restrict__ done,
    const float* __restrict__ Whh, const float* __restrict__ bhh,
    const float* __restrict__ gr,  const float* __restrict__ btr,
    const float* __restrict__ Wp,  const float* __restrict__ bp,
    const float* __restrict__ Wv,  const float* __restrict__ bv,
    const unsigned short* __restrict__ gxws, float* __restrict__ out)
{
    const int tid = threadIdx.x;
    const int b   = blockIdx.x;

    __shared__ __align__(16) _Float16 hsh[HH];
    __shared__ __align__(16) float ghl[3 * HH];
    __shared__ __align__(16) float yl[HH];
    __shared__ float hred[2][2];
    __shared__ _Float16 gxring[3][384];
    __shared__ int dsh[TT];

    const int l  = tid & 63;
    const int w  = tid >> 6;
    const int r  = (w << 5) | (l & 31);
    const int hf = (l >> 5) & 1;

    f16v w0, w1;   // half Whh row
    {
        const float2* p2 = (const float2*)(Whh + r * HH + hf * 64);
        LDW16(w0, p2, 0) LDW16(w1, p2, 16)
    }
    const float breg = bhh[r];

    float grr = 0.f, btrr = 0.f, hprev = 0.f;
    if (tid < HH) {
        grr = gr[tid]; btrr = btr[tid];
        hprev = hx[b * HH + tid];
        hsh[tid] = (_Float16)hprev;
    }

    f8v hw = {0.f,0.f,0.f,0.f,0.f,0.f,0.f,0.f};
    float bph = 0.f; int hg = 0, i16 = 0;
    const bool isHead = (tid >= 512) && (tid < 656);  // 9 tasks x 16 lanes
    if (isHead) {
        hg = (tid - 512) >> 4; i16 = (tid - 512) & 15;
        const float* wr = (hg < 8) ? (Wp + hg * HH) : Wv;
        hw[0]=wr[i16*8+0]; hw[1]=wr[i16*8+1]; hw[2]=wr[i16*8+2]; hw[3]=wr[i16*8+3];
        hw[4]=wr[i16*8+4]; hw[5]=wr[i16*8+5]; hw[6]=wr[i16*8+6]; hw[7]=wr[i16*8+7];
        bph = (hg < 8) ? bp[hg] : bv[0];
    }

    for (int idx = tid; idx < TT; idx += 768) dsh[idx] = done[b * TT + idx];

    const bool isStg = (tid >= 128) && (tid < 512);
    const int sid = tid - 128;
    if (isStg) {
        gxring[0][sid] = __builtin_bit_cast(_Float16, gxws[((size_t)b * TT + 0) * 384 + sid]);
        gxring[1][sid] = __builtin_bit_cast(_Float16, gxws[((size_t)b * TT + 1) * 384 + sid]);
    }
    __syncthreads();

    float hnew_keep = 0.f;
    const int VALO = BB * TT * AA;
    const int HFIN = VALO + BB * TT;

    for (int i = 0; i <= TT; ++i) {
        const bool live = i < TT;
        // SegA: stage gx(i+2); finalize y_{i-1}; gh matvec
        if (isStg && i + 2 < TT)
            gxring[(i + 2) % 3][sid] =
                __builtin_bit_cast(_Float16, gxws[((size_t)b * TT + i + 2) * 384 + sid]);
        if (tid < HH && i >= 1) {
            float s = hred[0][0] + hred[1][0];
            float q = hred[0][1] + hred[1][1];
            float mu = s * (1.f / 128.f);
            float rstd = rsqrtf(q * (1.f / 128.f) - mu * mu + 1e-5f);
            yl[tid] = (hnew_keep - mu) * rstd * grr + btrr;
        }
        if (live) {
            const float4* ph4 = ((const float4*)hsh) + hf * 8;
            float a0 = 0.f;
            HMV
            a0 += __shfl_xor(a0, 32);
            if ((l & 32) == 0) ghl[r] = a0 + breg;
        }
        __syncthreads();
        // SegB: GRU gates + LN partials; heads for t=i-1
        if (tid < HH && live) {
            int slot = i % 3;
            float xr_ = (float)gxring[slot][tid]          + ghl[tid];
            float xz_ = (float)gxring[slot][HH + tid]     + ghl[HH + tid];
            float xn_ = (float)gxring[slot][2 * HH + tid];
            float hn_ = ghl[2 * HH + tid];
            float r_ = 1.f / (1.f + __expf(-xr_));
            float u_ = 1.f / (1.f + __expf(-xz_));
            float a_ = xn_ + r_ * hn_;
            a_ = fminf(fmaxf(a_, -20.f), 20.f);
            float e2 = __expf(2.f * a_);
            float n_ = (e2 - 1.f) / (e2 + 1.f);
            float hn2 = (1.f - u_) * n_ + u_ * hprev;
            hnew_keep = hn2;
            float s = hn2, q = hn2 * hn2;
            #pragma unroll
            for (int m = 1; m < 64; m <<= 1) { s += __shfl_xor(s, m); q += __shfl_xor(q, m); }
            if (l == 0) { hred[w][0] = s; hred[w][1] = q; }
            float hm = hn2 * (dsh[i] ? 0.f : 1.f);
            hprev = hm;
            hsh[tid] = (_Float16)hm;
            if (i == TT - 1) out[HFIN + b * HH + tid] = hm;
        }
        if (isHead && i >= 1) {
            int t = i - 1;
            const float4* py = (const float4*)yl;
            float4 y0 = py[i16 * 2], y1 = py[i16 * 2 + 1];
            float p = y0.x*hw[0] + y0.y*hw[1] + y0.z*hw[2] + y0.w*hw[3]
                    + y1.x*hw[4] + y1.y*hw[5] + y1.z*hw[6] + y1.w*hw[7];
            p += __shfl_xor(p, 1); p += __shfl_xor(p, 2);
            p += __shfl_xor(p, 4); p += __shfl_xor(p, 8);
            if (i16 == 0) {
                if (hg < 8) out[((size_t)b * TT + t) * AA + hg] = p + bph;
                else        out[VALO + b * TT + t] = p + bph;
            }
        }
        __syncthreads();
    }
}

// ======================= FALLBACK (R6 kernel, used if ws too small) =======================
#define DOT4F(WV, J, UA, UB) \
    a0=dot2a(f2h(WV[(J)+0]),f2h(UA.x),a0); a1=dot2a(f2h(WV[(J)+0]),f2h(UB.x),a1); \
    a0=dot2a(f2h(WV[(J)+1]),f2h(UA.y),a0); a1=dot2a(f2h(WV[(J)+1]),f2h(UB.y),a1); \
    a0=dot2a(f2h(WV[(J)+2]),f2h(UA.z),a0); a1=dot2a(f2h(WV[(J)+2]),f2h(UB.z),a1); \
    a0=dot2a(f2h(WV[(J)+3]),f2h(UA.w),a0); a1=dot2a(f2h(WV[(J)+3]),f2h(UB.w),a1);
#define MVCF(WV, OFS) { float4 ua_, ub_; \
    ua_=pa4[(OFS)+0]; ub_=pb4[(OFS)+0]; DOT4F(WV,0, ua_,ub_) \
    ua_=pa4[(OFS)+1]; ub_=pb4[(OFS)+1]; DOT4F(WV,4, ua_,ub_) \
    ua_=pa4[(OFS)+2]; ub_=pb4[(OFS)+2]; DOT4F(WV,8, ua_,ub_) \
    ua_=pa4[(OFS)+3]; ub_=pb4[(OFS)+3]; DOT4F(WV,12,ua_,ub_) }
#define FDOT4F(WV, J, UX) \
    f0=dot2a(f2h(WV[(J)+0]),f2h(UX.x),f0); f1=dot2a(f2h(WV[(J)+1]),f2h(UX.y),f1); \
    f0=dot2a(f2h(WV[(J)+2]),f2h(UX.z),f0); f1=dot2a(f2h(WV[(J)+3]),f2h(UX.w),f1);
#define FEATMVF { float4 ux_; \
    ux_=px4[0]; FDOT4F(fw0,0, ux_) ux_=px4[1]; FDOT4F(fw0,4, ux_) \
    ux_=px4[2]; FDOT4F(fw0,8, ux_) ux_=px4[3]; FDOT4F(fw0,12,ux_) \
    ux_=px4[4]; FDOT4F(fw1,0, ux_) ux_=px4[5]; FDOT4F(fw1,4, ux_) \
    ux_=px4[6]; FDOT4F(fw1,8, ux_) ux_=px4[7]; FDOT4F(fw1,12,ux_) }

__global__ void
__attribute__((amdgpu_flat_work_group_size(768, 768), amdgpu_waves_per_eu(3, 3)))
rac_fb(
    const float* __restrict__ x,    const float* __restrict__ hx,
    const int*   __restrict__ done, const float* __restrict__ Wf,
    const float* __restrict__ bfe,  const float* __restrict__ gf,
    const float* __restrict__ btf,  const float* __restrict__ Wih,
    const float* __restrict__ Whh,  const float* __restrict__ bih,
    const float* __restrict__ bhh,  const float* __restrict__ gr,
    const float* __restrict__ btr,  const float* __restrict__ Wp,
    const float* __restrict__ bp,   const float* __restrict__ Wv,
    const float* __restrict__ bv,   float* __restrict__ out)
{
    const int tid = threadIdx.x;
    const int b0  = blockIdx.x * 2;

    __shared__ __align__(16) _Float16 zh[2][HH];
    __shared__ __align__(16) _Float16 hsh[2][HH];
    __shared__ __align__(16) _Float16 xh[2][SS];
    __shared__ __align__(16) float gxl[2][3*HH];
    __shared__ __align__(16) float ghl[2][3*HH];
    __shared__ __align__(16) float yl[2][HH];
    __shared__ __align__(16) float fraw[2][HH];
    __shared__ float fred[4][2];
    __shared__ float hred[4][2];
    __shared__ int   dsh[2][TT];

    const bool isGate = tid < 256;
    const bool isProd = tid < 384;
    const bool isFeat = (tid >= 256) && (tid < 512);
    const bool isXld  = (tid >= 512) && (tid < 640);
    const bool isHead = tid >= 512;

    f16v w0, w1, w2, w3;
    {
        const float* wsrc = isProd ? (Wih + tid * HH) : (Whh + (tid - 384) * HH);
        const float2* p2 = (const float2*)wsrc;
        LDW16(w0, p2, 0) LDW16(w1, p2, 16) LDW16(w2, p2, 32) LDW16(w3, p2, 48)
    }
    const float bias_mv = isProd ? bih[tid] : bhh[tid - 384];

    f16v fw0 = 0.f, fw1 = 0.f;
    float bfr = 0.f;
    int fc = 0, fj = 0;
    if (isFeat) {
        fc = (tid - 256) >> 7; fj = (tid - 256) & 127;
        const float2* p2 = (const float2*)(Wf + fj * SS);
        LDW16(fw0, p2, 0) LDW16(fw1, p2, 16)
        bfr = bfe[fj];
    }

    int gc = 0, gj = 0;
    float gfr = 0.f, btfr = 0.f, grr = 0.f, btrr = 0.f, hprev = 0.f;
    if (isGate) {
        gc = tid >> 7; gj = tid & 127;
        gfr = gf[gj]; btfr = btf[gj]; grr = gr[gj]; btrr = btr[gj];
        hprev = hx[(b0 + gc) * HH + gj];
        hsh[gc][gj] = (_Float16)hprev;
    }

    f8v hw0 = 0.f, hw1 = 0.f;
    float bp0 = 0.f, bp1 = 0.f;
    int hi16 = 0, tk0 = 0, tk1 = -1;
    if (isHead) {
        int hid = tid - 512; int hg2 = hid >> 4; hi16 = hid & 15;
        tk0 = hg2; tk1 = (hg2 < 2) ? (16 + hg2) : -1;
        {
            int k = tk0 % 9;
            const float* wr = (k < 8) ? (Wp + k * HH) : Wv;
            hw0[0]=wr[hi16*8+0]; hw0[1]=wr[hi16*8+1]; hw0[2]=wr[hi16*8+2]; hw0[3]=wr[hi16*8+3];
            hw0[4]=wr[hi16*8+4]; hw0[5]=wr[hi16*8+5]; hw0[6]=wr[hi16*8+6]; hw0[7]=wr[hi16*8+7];
            bp0 = (k < 8) ? bp[k] : bv[0];
        }
        if (tk1 >= 0) {
            int k = tk1 % 9;
            const float* wr = (k < 8) ? (Wp + k * HH) : Wv;
            hw1[0]=wr[hi16*8+0]; hw1[1]=wr[hi16*8+1]; hw1[2]=wr[hi16*8+2]; hw1[3]=wr[hi16*8+3];
            hw1[4]=wr[hi16*8+4]; hw1[5]=wr[hi16*8+5]; hw1[6]=wr[hi16*8+6]; hw1[7]=wr[hi16*8+7];
            bp1 = (k < 8) ? bp[k] : bv[0];
        }
    }

    for (int idx = tid; idx < 2 * TT; idx += 768)
        dsh[idx >> 9][idx & 511] = done[(b0 + (idx >> 9)) * TT + (idx & 511)];

    int xc = 0, xe = 0;
    const float* xbase = nullptr;
    float xr0 = 0.f, xr1 = 0.f;
    if (isXld) {
        int xi = tid - 512; xc = xi >> 6; xe = xi & 63;
        xbase = x + (size_t)(b0 + xc) * TT * SS + xe;
        float xa = xbase[0];
        xr1 = xbase[SS];
        xr0 = xbase[2 * SS];
        xh[xc][xe] = (_Float16)xa;
    }
    __syncthreads();

    if (isFeat) {
        float f0 = bfr, f1 = 0.f;
        const float4* px4 = (const float4*)xh[fc];
        FEATMVF
        float fv = f0 + f1;
        fraw[fc][fj] = fv;
        float s = fv, q = fv * fv;
        #pragma unroll
        for (int m = 1; m < 64; m <<= 1) { s += __shfl_xor(s, m); q += __shfl_xor(q, m); }
        if ((tid & 63) == 0) { int w = (tid >> 6) - 4; fred[w][0] = s; fred[w][1] = q; }
    }
    __syncthreads();
    if (isGate) {
        float s = fred[2 * gc][0] + fred[2 * gc + 1][0];
        float q = fred[2 * gc][1] + fred[2 * gc + 1][1];
        float mu = s * (1.f / 128.f);
        float rstd = rsqrtf(q * (1.f / 128.f) - mu * mu + 1e-5f);
        float z = (fraw[gc][gj] - mu) * rstd * gfr + btfr;
        zh[gc][gj] = (_Float16)fmaxf(z, 0.f);
    }
    if (isXld) xh[xc][xe] = (_Float16)xr1;
    __syncthreads();

    float hnew_keep = 0.f;
    const int VALO = BB * TT * AA;
    const int HFIN = VALO + BB * TT;

    for (int i = 0; i <= TT; ++i) {
        const bool live = i < TT;
        if (isXld && i < TT - 3) {
            float v = xbase[(size_t)(i + 3) * SS];
            if (((i + 3) & 1) == 0) xr0 = v; else xr1 = v;
        }
        if (isGate && i >= 1) {
            float s = hred[2 * gc][0] + hred[2 * gc + 1][0];
            float q = hred[2 * gc][1] + hred[2 * gc + 1][1];
            float mu = s * (1.f / 128.f);
            float rstd = rsqrtf(q * (1.f / 128.f) - mu * mu + 1e-5f);
            yl[gc][gj] = (hnew_keep - mu) * rstd * grr + btrr;
        }
        if (live) {
            const float4* pa4; const float4* pb4; int r;
            if (isProd) { pa4 = (const float4*)zh[0];  pb4 = (const float4*)zh[1];  r = tid; }
            else        { pa4 = (const float4*)hsh[0]; pb4 = (const float4*)hsh[1]; r = tid - 384; }
            float a0 = bias_mv, a1 = bias_mv;
            MVCF(w0, 0) MVCF(w1, 4) MVCF(w2, 8) MVCF(w3, 12)
            if (isProd) { gxl[0][r] = a0; gxl[1][r] = a1; }
            else        { ghl[0][r] = a0; ghl[1][r] = a1; }
        }
        if (isFeat && i < TT - 1) {
            float f0 = bfr, f1 = 0.f;
            const float4* px4 = (const float4*)xh[fc];
            FEATMVF
            float fv = f0 + f1;
            fraw[fc][fj] = fv;
            float s = fv, q = fv * fv;
            #pragma unroll
            for (int m = 1; m < 64; m <<= 1) { s += __shfl_xor(s, m); q += __shfl_xor(q, m); }
            if ((tid & 63) == 0) { int w = (tid >> 6) - 4; fred[w][0] = s; fred[w][1] = q; }
        }
        __syncthreads();
        if (isGate) {
            if (i < TT - 1) {
                float s = fred[2 * gc][0] + fred[2 * gc + 1][0];
                float q = fred[2 * gc][1] + fred[2 * gc + 1][1];
                float mu = s * (1.f / 128.f);
                float rstd = rsqrtf(q * (1.f / 128.f) - mu * mu + 1e-5f);
                float z = (fraw[gc][gj] - mu) * rstd * gfr + btfr;
                zh[gc][gj] = (_Float16)fmaxf(z, 0.f);
            }
            if (live) {
                float xr_ = gxl[gc][gj],          hr_ = ghl[gc][gj];
                float xz_ = gxl[gc][HH + gj],     hz_ = ghl[gc][HH + gj];
                float xn_ = gxl[gc][2 * HH + gj], hn_ = ghl[gc][2 * HH + gj];
                float r_ = 1.f / (1.f + __expf(-(xr_ + hr_)));
                float u_ = 1.f / (1.f + __expf(-(xz_ + hz_)));
                float a_ = xn_ + r_ * hn_;
                a_ = fminf(fmaxf(a_, -20.f), 20.f);
                float e2 = __expf(2.f * a_);
                float n_ = (e2 - 1.f) / (e2 + 1.f);
                float hn2 = (1.f - u_) * n_ + u_ * hprev;
                hnew_keep = hn2;
                float s = hn2, q = hn2 * hn2;
                #pragma unroll
                for (int m = 1; m < 64; m <<= 1) { s += __shfl_xor(s, m); q += __shfl_xor(q, m); }
                if ((tid & 63) == 0) { int w = tid >> 6; hred[w][0] = s; hred[w][1] = q; }
                float hm = hn2 * (dsh[gc][i] ? 0.f : 1.f);
                hprev = hm;
                hsh[gc][gj] = (_Float16)hm;
                if (i == TT - 1) out[HFIN + (b0 + gc) * HH + gj] = hm;
            }
        }
        if (isHead && i >= 1) {
            int t = i - 1;
            {
                int c = tk0 / 9, k = tk0 % 9;
                const float4* py = (const float4*)yl[c];
                float4 y0 = py[hi16 * 2], y1 = py[hi16 * 2 + 1];
                float p = y0.x*hw0[0] + y0.y*hw0[1] + y0.z*hw0[2] + y0.w*hw0[3]
                        + y1.x*hw0[4] + y1.y*hw0[5] + y1.z*hw0[6] + y1.w*hw0[7];
                #pragma unroll
                for (int m = 8; m >= 1; m >>= 1) p += __shfl_xor(p, m);
                if (hi16 == 0) {
                    int bc = b0 + c;
                    if (k < 8) out[((size_t)bc * TT + t) * AA + k] = p + bp0;
                    else       out[VALO + bc * TT + t] = p + bp0;
                }
            }
            if (tk1 >= 0) {
                int c = tk1 / 9, k = tk1 % 9;
                const float4* py = (const float4*)yl[c];
                float4 y0 = py[hi16 * 2], y1 = py[hi16 * 2 + 1];
                float p = y0.x*hw1[0] + y0.y*hw1[1] + y0.z*hw1[2] + y0.w*hw1[3]
                        + y1.x*hw1[4] + y1.y*hw1[5] + y1.z*hw1[6] + y1.w*hw1[7];
                #pragma unroll
                for (int m = 8; m >= 1; m >>= 1) p += __shfl_xor(p, m);
                if (hi16 == 0) {
                    int bc = b0 + c;
                    if (k < 8) out[((size_t)bc * TT + t) * AA + k] = p + bp1;
                    else       out[VALO + bc * TT + t] = p + bp1;
                }
            }
        }
        if (isXld && i < TT - 2) {
            float v = (((i + 2) & 1) == 0) ? xr0 : xr1;
            xh[xc][xe] = (_Float16)v;
        }
        __syncthreads();
    }
}

extern "C" void kernel_launch(void* const* d_in, const int* in_sizes, int n_in,
                              void* d_out, int out_size, void* d_ws, size_t ws_size,
                              hipStream_t stream) {
    const float* x   = (const float*)d_in[0];
    const float* hx  = (const float*)d_in[1];
    const int*   dn  = (const int*)d_in[2];
    const float* Wf  = (const float*)d_in[3];
    const float* bfe = (const float*)d_in[4];
    const float* gf  = (const float*)d_in[5];
    const float* btf = (const float*)d_in[6];
    const float* Wih = (const float*)d_in[7];
    const float* Whh = (const float*)d_in[8];
    const float* bih = (const float*)d_in[9];
    const float* bhh = (const float*)d_in[10];
    const float* gr  = (const float*)d_in[11];
    const float* btr = (const float*)d_in[12];
    const float* Wp  = (const float*)d_in[13];
    const float* bp  = (const float*)d_in[14];
    const float* Wv  = (const float*)d_in[15];
    const float* bv  = (const float*)d_in[16];
    float* out = (float*)d_out;

    const size_t need = (size_t)BB * TT * 384 * 2;   // 201.3 MB fp16 gx
    if (ws_size >= need) {
        unsigned short* gxws = (unsigned short*)d_ws;
        hipLaunchKernelGGL(p1_kernel, dim3(BB * 4), dim3(768), 0, stream,
                           x, Wf, bfe, gf, btf, Wih, bih, gxws);
        hipLaunchKernelGGL(p2_kernel, dim3(BB), dim3(768), 0, stream,
                           hx, dn, Whh, bhh, gr, btr, Wp, bp, Wv, bv, gxws, out);
    } else {
        hipLaunchKernelGGL(rac_fb, dim3(BB / 2), dim3(768), 0, stream,
                           x, hx, dn, Wf, bfe, gf, btf, Wih, Whh, bih, bhh,
                           gr, btr, Wp, bp, Wv, bv, out);
    }
}

// Round 8
// 2136.599 us; speedup vs baseline: 1.0237x; 1.0237x over previous
//
#include <hip/hip_runtime.h>

// RecurrentActorCritic B=512,T=512,S=64,H=128,A=8 (fp32 I/O). Two phases:
//  p1: gx = Wih@relu(LN(x@Wf^T)) for all (b,t) -> d_ws fp16 (201 MB).
//  p2: sequential GRU scan, 1 chain/block, half Whh row/thread in regs.
// R7 post-mortem: both phases ~2.15us/step = ~5200cyc, ~90% stall. Cause:
// __syncthreads drains vmcnt(0) (global load latency + store-acks) every
// segment; gxws prefetch was load->immediate ds_write (zero slack).
// R8: raw "s_waitcnt lgkmcnt(0); s_barrier" (LDS-only drain, vmcnt stays in
// flight); gx staged in 16-step double-buffered LDS chunks via registers
// (16 steps of slack); h-LN reduce moved off gate critical path (wave 2,
// SegA of next step; heads lag 2); 4-way independent dot2 chains.

typedef _Float16 h2t __attribute__((ext_vector_type(2)));
typedef float f16v __attribute__((ext_vector_type(16)));
typedef float f8v  __attribute__((ext_vector_type(8)));

__device__ __forceinline__ float dot2a(h2t a, h2t b, float c) {
    return __builtin_amdgcn_fdot2(a, b, c, false);
}
__device__ __forceinline__ h2t f2h(float f) { return __builtin_bit_cast(h2t, f); }
__device__ __forceinline__ float pk2(float lo, float hi) {
    h2t a; a.x = (_Float16)lo; a.y = (_Float16)hi;
    return __builtin_bit_cast(float, a);
}

// LDS-only barrier: drain ds ops, leave global loads/stores in flight.
#define BAR() __asm__ volatile("s_waitcnt lgkmcnt(0)\n\ts_barrier" ::: "memory")

#define BB 512
#define TT 512
#define SS 64
#define HH 128
#define AA 8
#define CH 128            // p1 time chunk
#define CK 16             // p2 gx chunk steps
#define NCK (TT / CK)

#define LDW16(WV, P2, OFS) { float2 v_; \
    v_=(P2)[(OFS)+0];  WV[0] =pk2(v_.x,v_.y); v_=(P2)[(OFS)+1];  WV[1] =pk2(v_.x,v_.y); \
    v_=(P2)[(OFS)+2];  WV[2] =pk2(v_.x,v_.y); v_=(P2)[(OFS)+3];  WV[3] =pk2(v_.x,v_.y); \
    v_=(P2)[(OFS)+4];  WV[4] =pk2(v_.x,v_.y); v_=(P2)[(OFS)+5];  WV[5] =pk2(v_.x,v_.y); \
    v_=(P2)[(OFS)+6];  WV[6] =pk2(v_.x,v_.y); v_=(P2)[(OFS)+7];  WV[7] =pk2(v_.x,v_.y); \
    v_=(P2)[(OFS)+8];  WV[8] =pk2(v_.x,v_.y); v_=(P2)[(OFS)+9];  WV[9] =pk2(v_.x,v_.y); \
    v_=(P2)[(OFS)+10]; WV[10]=pk2(v_.x,v_.y); v_=(P2)[(OFS)+11]; WV[11]=pk2(v_.x,v_.y); \
    v_=(P2)[(OFS)+12]; WV[12]=pk2(v_.x,v_.y); v_=(P2)[(OFS)+13]; WV[13]=pk2(v_.x,v_.y); \
    v_=(P2)[(OFS)+14]; WV[14]=pk2(v_.x,v_.y); v_=(P2)[(OFS)+15]; WV[15]=pk2(v_.x,v_.y); }

#define LDW8(WV, P2, OFS) { float2 v_; \
    v_=(P2)[(OFS)+0]; WV[0]=pk2(v_.x,v_.y); v_=(P2)[(OFS)+1]; WV[1]=pk2(v_.x,v_.y); \
    v_=(P2)[(OFS)+2]; WV[2]=pk2(v_.x,v_.y); v_=(P2)[(OFS)+3]; WV[3]=pk2(v_.x,v_.y); \
    v_=(P2)[(OFS)+4]; WV[4]=pk2(v_.x,v_.y); v_=(P2)[(OFS)+5]; WV[5]=pk2(v_.x,v_.y); \
    v_=(P2)[(OFS)+6]; WV[6]=pk2(v_.x,v_.y); v_=(P2)[(OFS)+7]; WV[7]=pk2(v_.x,v_.y); }

// half-row (w0,w1) dot LDS vec at ph4 (8 float4), 4 independent chains -> A0
#define HMVX(A0) { float4 u_; float c0_=0.f,c1_=0.f,c2_=0.f,c3_=0.f; \
  u_=ph4[0]; c0_=dot2a(f2h(w0[0]), f2h(u_.x),c0_); c0_=dot2a(f2h(w0[1]), f2h(u_.y),c0_); c0_=dot2a(f2h(w0[2]), f2h(u_.z),c0_); c0_=dot2a(f2h(w0[3]), f2h(u_.w),c0_); \
  u_=ph4[1]; c1_=dot2a(f2h(w0[4]), f2h(u_.x),c1_); c1_=dot2a(f2h(w0[5]), f2h(u_.y),c1_); c1_=dot2a(f2h(w0[6]), f2h(u_.z),c1_); c1_=dot2a(f2h(w0[7]), f2h(u_.w),c1_); \
  u_=ph4[2]; c2_=dot2a(f2h(w0[8]), f2h(u_.x),c2_); c2_=dot2a(f2h(w0[9]), f2h(u_.y),c2_); c2_=dot2a(f2h(w0[10]),f2h(u_.z),c2_); c2_=dot2a(f2h(w0[11]),f2h(u_.w),c2_); \
  u_=ph4[3]; c3_=dot2a(f2h(w0[12]),f2h(u_.x),c3_); c3_=dot2a(f2h(w0[13]),f2h(u_.y),c3_); c3_=dot2a(f2h(w0[14]),f2h(u_.z),c3_); c3_=dot2a(f2h(w0[15]),f2h(u_.w),c3_); \
  u_=ph4[4]; c0_=dot2a(f2h(w1[0]), f2h(u_.x),c0_); c0_=dot2a(f2h(w1[1]), f2h(u_.y),c0_); c0_=dot2a(f2h(w1[2]), f2h(u_.z),c0_); c0_=dot2a(f2h(w1[3]), f2h(u_.w),c0_); \
  u_=ph4[5]; c1_=dot2a(f2h(w1[4]), f2h(u_.x),c1_); c1_=dot2a(f2h(w1[5]), f2h(u_.y),c1_); c1_=dot2a(f2h(w1[6]), f2h(u_.z),c1_); c1_=dot2a(f2h(w1[7]), f2h(u_.w),c1_); \
  u_=ph4[6]; c2_=dot2a(f2h(w1[8]), f2h(u_.x),c2_); c2_=dot2a(f2h(w1[9]), f2h(u_.y),c2_); c2_=dot2a(f2h(w1[10]),f2h(u_.z),c2_); c2_=dot2a(f2h(w1[11]),f2h(u_.w),c2_); \
  u_=ph4[7]; c3_=dot2a(f2h(w1[12]),f2h(u_.x),c3_); c3_=dot2a(f2h(w1[13]),f2h(u_.y),c3_); c3_=dot2a(f2h(w1[14]),f2h(u_.z),c3_); c3_=dot2a(f2h(w1[15]),f2h(u_.w),c3_); \
  A0 = (c0_ + c1_) + (c2_ + c3_); }

#define FD4(WV, J, U) \
    f0=dot2a(f2h(WV[(J)+0]),f2h(U.x),f0); f1=dot2a(f2h(WV[(J)+1]),f2h(U.y),f1); \
    f0=dot2a(f2h(WV[(J)+2]),f2h(U.z),f0); f1=dot2a(f2h(WV[(J)+3]),f2h(U.w),f1);

// ======================= PHASE 1 =======================
__global__ void __launch_bounds__(768, 2) p1_kernel(
    const float* __restrict__ x,   const float* __restrict__ Wf,
    const float* __restrict__ bfe, const float* __restrict__ gf,
    const float* __restrict__ btf, const float* __restrict__ Wih,
    const float* __restrict__ bih, unsigned short* __restrict__ gxws)
{
    const int tid = threadIdx.x;
    const int b  = blockIdx.x >> 2;
    const int t0 = (blockIdx.x & 3) * CH;

    __shared__ __align__(16) _Float16 xh2[CH][SS];
    __shared__ __align__(16) _Float16 zh[HH];
    __shared__ __align__(16) float fraw[HH];
    __shared__ float fred[8][2];

    const int l  = tid & 63;
    const int w  = tid >> 6;
    const int r  = (w << 5) | (l & 31);
    const int hf = (l >> 5) & 1;

    f16v w0, w1;
    {
        const float2* p2 = (const float2*)(Wih + r * HH + hf * 64);
        LDW16(w0, p2, 0) LDW16(w1, p2, 16)
    }
    const float breg = bih[r];

    f8v fw = {0.f,0.f,0.f,0.f,0.f,0.f,0.f,0.f};
    float bfr = 0.f;
    int fq = 0, fr = 0;
    if (tid >= 256) {
        int idx = tid - 256;
        fq = idx & 3; fr = idx >> 2;
        const float2* p2 = (const float2*)(Wf + fr * SS + fq * 16);
        LDW8(fw, p2, 0)
        bfr = bfe[fr];
    }
    float gfr = 0.f, btfr = 0.f;
    if (tid < HH) { gfr = gf[tid]; btfr = btf[tid]; }

    for (int idx = tid; idx < CH * SS; idx += 768) {
        int tl = idx >> 6, e = idx & 63;
        xh2[tl][e] = (_Float16)x[((size_t)b * TT + t0 + tl) * SS + e];
    }
    __syncthreads();

    for (int tt = 0; tt < CH; ++tt) {
        // SegA: feature dots + LN partials
        if (tid >= 256) {
            const float4* px4 = ((const float4*)xh2[tt]) + fq * 2;
            float f0 = 0.f, f1 = 0.f;
            float4 u_;
            u_ = px4[0]; FD4(fw, 0, u_)
            u_ = px4[1]; FD4(fw, 4, u_)
            float p = f0 + f1;
            p += __shfl_xor(p, 1);
            p += __shfl_xor(p, 2);
            p += bfr;
            if (fq == 0) fraw[fr] = p;
            float s = p * 0.25f, q = p * p * 0.25f;
            #pragma unroll
            for (int m = 1; m < 64; m <<= 1) { s += __shfl_xor(s, m); q += __shfl_xor(q, m); }
            if (l == 0) { fred[w - 4][0] = s; fred[w - 4][1] = q; }
        }
        BAR();
        // SegB: LN + relu -> zh
        if (tid < HH) {
            float s = fred[0][0]+fred[1][0]+fred[2][0]+fred[3][0]
                    + fred[4][0]+fred[5][0]+fred[6][0]+fred[7][0];
            float q = fred[0][1]+fred[1][1]+fred[2][1]+fred[3][1]
                    + fred[4][1]+fred[5][1]+fred[6][1]+fred[7][1];
            float mu = s * (1.f / 128.f);
            float rstd = rsqrtf(q * (1.f / 128.f) - mu * mu + 1e-5f);
            float z = (fraw[tid] - mu) * rstd * gfr + btfr;
            zh[tid] = (_Float16)fmaxf(z, 0.f);
        }
        BAR();
        // SegC: gx half-row matvec + fp16 store (store-acks never drained)
        {
            const float4* ph4 = ((const float4*)zh) + hf * 8;
            float a0;
            HMVX(a0)
            a0 += __shfl_xor(a0, 32);
            if ((l & 32) == 0) {
                _Float16 g = (_Float16)(a0 + breg);
                gxws[((size_t)b * TT + t0 + tt) * 384 + r] =
                    __builtin_bit_cast(unsigned short, g);
            }
        }
    }
}

// ======================= PHASE 2 =======================
__global__ void __launch_bounds__(768, 2) p2_kernel(
    const float* __restrict__ hx,  const int* __restrict__ done,
    const float* __restrict__ Whh, const float* __restrict__ bhh,
    const float* __restrict__ gr,  const float* __restrict__ btr,
    const float* __restrict__ Wp,  const float* __restrict__ bp,
    const float* __restrict__ Wv,  const float* __restrict__ bv,
    const unsigned short* __restrict__ gxws, float* __restrict__ out)
{
    const int tid = threadIdx.x;
    const int b   = blockIdx.x;

    __shared__ __align__(16) _Float16 hsh[HH];
    __shared__ __align__(16) float ghl[3 * HH];
    __shared__ __align__(16) float yl[HH];
    __shared__ __align__(16) float hnb[HH];
    __shared__ float hredS[2];
    __shared__ __align__(16) _Float16 gxb[2][CK][384];   // 24 KB double buffer
    __shared__ int dsh[TT];

    const int l  = tid & 63;
    const int w  = tid >> 6;
    const int r  = (w << 5) | (l & 31);
    const int hf = (l >> 5) & 1;

    f16v w0, w1;
    {
        const float2* p2 = (const float2*)(Whh + r * HH + hf * 64);
        LDW16(w0, p2, 0) LDW16(w1, p2, 16)
    }
    const float breg = bhh[r];

    float grr = 0.f, btrr = 0.f, hprev = 0.f, hnew_prev = 0.f;
    if (tid < HH) {
        grr = gr[tid]; btrr = btr[tid];
        hprev = hx[b * HH + tid];
        hsh[tid] = (_Float16)hprev;
    }

    const bool isRed = (tid >= 128) && (tid < 192);  // wave 2: h-LN reduce
    const int  rl    = tid - 128;

    f8v hw = {0.f,0.f,0.f,0.f,0.f,0.f,0.f,0.f};
    float bph = 0.f; int hg = 0, i16 = 0;
    const bool isHead = (tid >= 512) && (tid < 656);
    if (isHead) {
        hg = (tid - 512) >> 4; i16 = (tid - 512) & 15;
        const float* wr = (hg < 8) ? (Wp + hg * HH) : Wv;
        hw[0]=wr[i16*8+0]; hw[1]=wr[i16*8+1]; hw[2]=wr[i16*8+2]; hw[3]=wr[i16*8+3];
        hw[4]=wr[i16*8+4]; hw[5]=wr[i16*8+5]; hw[6]=wr[i16*8+6]; hw[7]=wr[i16*8+7];
        bph = (hg < 8) ? bp[hg] : bv[0];
    }

    for (int idx = tid; idx < TT; idx += 768) dsh[idx] = done[b * TT + idx];

    // gx staging: 384 threads (128-511), ushort4 granules; 96 u4 per step.
    const bool isStg = (tid >= 128) && (tid < 512);
    const int  s    = tid - 128;
    const int  jgrp = s / 96;          // 0..3
    const int  col4 = s - jgrp * 96;   // 0..95
    const unsigned short* base = gxws + (size_t)b * TT * 384;
    ushort4 r0, r1, r2, r3;

    if (isStg) {   // chunk 0: load + write immediately
        r0 = *(const ushort4*)(base + (size_t)(jgrp +  0) * 384 + col4 * 4);
        r1 = *(const ushort4*)(base + (size_t)(jgrp +  4) * 384 + col4 * 4);
        r2 = *(const ushort4*)(base + (size_t)(jgrp +  8) * 384 + col4 * 4);
        r3 = *(const ushort4*)(base + (size_t)(jgrp + 12) * 384 + col4 * 4);
        *(ushort4*)&gxb[0][jgrp +  0][col4 * 4] = r0;
        *(ushort4*)&gxb[0][jgrp +  4][col4 * 4] = r1;
        *(ushort4*)&gxb[0][jgrp +  8][col4 * 4] = r2;
        *(ushort4*)&gxb[0][jgrp + 12][col4 * 4] = r3;
    }
    __syncthreads();

    const int VALO = BB * TT * AA;
    const int HFIN = VALO + BB * TT;

    for (int c = 0; c < NCK; ++c) {
        const int cb = c & 1;
        if (isStg && c + 1 < NCK) {   // issue next-chunk loads; 16 steps of slack
            const unsigned short* cb2 = base + (size_t)(c + 1) * CK * 384;
            r0 = *(const ushort4*)(cb2 + (size_t)(jgrp +  0) * 384 + col4 * 4);
            r1 = *(const ushort4*)(cb2 + (size_t)(jgrp +  4) * 384 + col4 * 4);
            r2 = *(const ushort4*)(cb2 + (size_t)(jgrp +  8) * 384 + col4 * 4);
            r3 = *(const ushort4*)(cb2 + (size_t)(jgrp + 12) * 384 + col4 * 4);
        }
        for (int j = 0; j < CK; ++j) {
            const int i = c * CK + j;
            // ---- SegA: matvec + (wave2) h-LN reduce + heads(t=i-2) ----
            if (isRed && i >= 1) {
                float a = hnb[rl], bq = hnb[rl + 64];
                float sv = a + bq, qv = a * a + bq * bq;
                #pragma unroll
                for (int m = 1; m < 64; m <<= 1) { sv += __shfl_xor(sv, m); qv += __shfl_xor(qv, m); }
                if (rl == 0) { hredS[0] = sv; hredS[1] = qv; }
            }
            if (isHead && i >= 2) {
                int t = i - 2;
                const float4* py = (const float4*)yl;
                float4 y0 = py[i16 * 2], y1 = py[i16 * 2 + 1];
                float p = y0.x*hw[0] + y0.y*hw[1] + y0.z*hw[2] + y0.w*hw[3]
                        + y1.x*hw[4] + y1.y*hw[5] + y1.z*hw[6] + y1.w*hw[7];
                p += __shfl_xor(p, 1); p += __shfl_xor(p, 2);
                p += __shfl_xor(p, 4); p += __shfl_xor(p, 8);
                if (i16 == 0) {
                    if (hg < 8) out[((size_t)b * TT + t) * AA + hg] = p + bph;
                    else        out[VALO + b * TT + t] = p + bph;
                }
            }
            {
                const float4* ph4 = ((const float4*)hsh) + hf * 8;
                float a0;
                HMVX(a0)
                a0 += __shfl_xor(a0, 32);
                if ((l & 32) == 0) ghl[r] = a0 + breg;
            }
            BAR();
            // ---- SegB: gates (+ y-finalize for i-1) ----
            if (tid < HH) {
                if (i >= 1) {
                    float sv = hredS[0], qv = hredS[1];
                    float mu = sv * (1.f / 128.f);
                    float rstd = rsqrtf(qv * (1.f / 128.f) - mu * mu + 1e-5f);
                    yl[tid] = (hnew_prev - mu) * rstd * grr + btrr;
                }
                float xr_ = (float)gxb[cb][j][tid]          + ghl[tid];
                float xz_ = (float)gxb[cb][j][HH + tid]     + ghl[HH + tid];
                float xn_ = (float)gxb[cb][j][2 * HH + tid];
                float hn_ = ghl[2 * HH + tid];
                float r_ = 1.f / (1.f + __expf(-xr_));
                float u_ = 1.f / (1.f + __expf(-xz_));
                float a_ = xn_ + r_ * hn_;
                a_ = fminf(fmaxf(a_, -20.f), 20.f);
                float e2 = __expf(2.f * a_);
                float n_ = (e2 - 1.f) / (e2 + 1.f);
                float hn2 = (1.f - u_) * n_ + u_ * hprev;
                hnb[tid] = hn2;
                hnew_prev = hn2;
                float hm = hn2 * (dsh[i] ? 0.f : 1.f);
                hprev = hm;
                hsh[tid] = (_Float16)hm;
                if (i == TT - 1) out[HFIN + b * HH + tid] = hm;
            }
            BAR();
        }
        if (isStg && c + 1 < NCK) {   // write staged regs; vmcnt wait has 16 steps slack
            const int nb = cb ^ 1;
            *(ushort4*)&gxb[nb][jgrp +  0][col4 * 4] = r0;
            *(ushort4*)&gxb[nb][jgrp +  4][col4 * 4] = r1;
            *(ushort4*)&gxb[nb][jgrp +  8][col4 * 4] = r2;
            *(ushort4*)&gxb[nb][jgrp + 12][col4 * 4] = r3;
        }
    }

    // ---- epilogue: i = TT (reduce + heads t=TT-2; y-finalize), i = TT+1 (heads t=TT-1)
    if (isRed) {
        float a = hnb[rl], bq = hnb[rl + 64];
        float sv = a + bq, qv = a * a + bq * bq;
        #pragma unroll
        for (int m = 1; m < 64; m <<= 1) { sv += __shfl_xor(sv, m); qv += __shfl_xor(qv, m); }
        if (rl == 0) { hredS[0] = sv; hredS[1] = qv; }
    }
    if (isHead) {
        int t = TT - 2;
        const float4* py = (const float4*)yl;
        float4 y0 = py[i16 * 2], y1 = py[i16 * 2 + 1];
        float p = y0.x*hw[0] + y0.y*hw[1] + y0.z*hw[2] + y0.w*hw[3]
                + y1.x*hw[4] + y1.y*hw[5] + y1.z*hw[6] + y1.w*hw[7];
        p += __shfl_xor(p, 1); p += __shfl_xor(p, 2);
        p += __shfl_xor(p, 4); p += __shfl_xor(p, 8);
        if (i16 == 0) {
            if (hg < 8) out[((size_t)b * TT + t) * AA + hg] = p + bph;
            else        out[VALO + b * TT + t] = p + bph;
        }
    }
    BAR();
    if (tid < HH) {
        float sv = hredS[0], qv = hredS[1];
        float mu = sv * (1.f / 128.f);
        float rstd = rsqrtf(qv * (1.f / 128.f) - mu * mu + 1e-5f);
        yl[tid] = (hnew_prev - mu) * rstd * grr + btrr;
    }
    BAR();
    if (isHead) {
        int t = TT - 1;
        const float4* py = (const float4*)yl;
        float4 y0 = py[i16 * 2], y1 = py[i16 * 2 + 1];
        float p = y0.x*hw[0] + y0.y*hw[1] + y0.z*hw[2] + y0.w*hw[3]
                + y1.x*hw[4] + y1.y*hw[5] + y1.z*hw[6] + y1.w*hw[7];
        p += __shfl_xor(p, 1); p += __shfl_xor(p, 2);
        p += __shfl_xor(p, 4); p += __shfl_xor(p, 8);
        if (i16 == 0) {
            if (hg < 8) out[((size_t)b * TT + t) * AA + hg] = p + bph;
            else        out[VALO + b * TT + t] = p + bph;
        }
    }
}

extern "C" void kernel_launch(void* const* d_in, const int* in_sizes, int n_in,
                              void* d_out, int out_size, void* d_ws, size_t ws_size,
                              hipStream_t stream) {
    const float* x   = (const float*)d_in[0];
    const float* hx  = (const float*)d_in[1];
    const int*   dn  = (const int*)d_in[2];
    const float* Wf  = (const float*)d_in[3];
    const float* bfe = (const float*)d_in[4];
    const float* gf  = (const float*)d_in[5];
    const float* btf = (const float*)d_in[6];
    const float* Wih = (const float*)d_in[7];
    const float* Whh = (const float*)d_in[8];
    const float* bih = (const float*)d_in[9];
    const float* bhh = (const float*)d_in[10];
    const float* gr  = (const float*)d_in[11];
    const float* btr = (const float*)d_in[12];
    const float* Wp  = (const float*)d_in[13];
    const float* bp  = (const float*)d_in[14];
    const float* Wv  = (const float*)d_in[15];
    const float* bv  = (const float*)d_in[16];
    float* out = (float*)d_out;

    unsigned short* gxws = (unsigned short*)d_ws;   // 201.3 MB, fits (R7 ran this path)
    hipLaunchKernelGGL(p1_kernel, dim3(BB * 4), dim3(768), 0, stream,
                       x, Wf, bfe, gf, btf, Wih, bih, gxws);
    hipLaunchKernelGGL(p2_kernel, dim3(BB), dim3(768), 0, stream,
                       hx, dn, Whh, bhh, gr, btr, Wp, bp, Wv, bv, gxws, out);
}

// Round 9
// 1509.884 us; speedup vs baseline: 1.4486x; 1.4151x over previous
//
#include <hip/hip_runtime.h>

// RecurrentActorCritic B=512,T=512,S=64,H=128,A=8 (fp32 I/O).
// R8 post-mortem: ~2us per barrier-round in both phases = dependent
// __shfl_xor chains (ds_permute ~120cyc each, 6-deep = 720cyc) inside every
// barrier segment; BAR's lgkmcnt(0) drain makes them the step length.
// R9: (a) LN(h_new) is NOT on the recurrence path -> p2 inner loop is
// matvec+gates only (one shfl); LN+y+heads for chunk c-1 run as bulk bursts
// during chunk c with ZERO cross-lane ops (serial sums, one-thread-per-output
// dots from LDS, 132-float padded rows). (b) p1 batches 16 t per barrier
// round (shfl chains pipeline across t), LN stats via serial sums.
// Half-row weights (32 VGPR) everywhere -> safely under the 84-reg cap.

typedef _Float16 h2t __attribute__((ext_vector_type(2)));
typedef float f16v __attribute__((ext_vector_type(16)));

__device__ __forceinline__ float dot2a(h2t a, h2t b, float c) {
    return __builtin_amdgcn_fdot2(a, b, c, false);
}
__device__ __forceinline__ h2t f2h(float f) { return __builtin_bit_cast(h2t, f); }
__device__ __forceinline__ float pk2(float lo, float hi) {
    h2t a; a.x = (_Float16)lo; a.y = (_Float16)hi;
    return __builtin_bit_cast(float, a);
}
__device__ __forceinline__ unsigned short hpk(float v) {
    return __builtin_bit_cast(unsigned short, (_Float16)v);
}

// LDS-only barrier: drain ds ops, leave global loads/stores in flight.
#define BAR() __asm__ volatile("s_waitcnt lgkmcnt(0)\n\ts_barrier" ::: "memory")

#define BB 512
#define TT 512
#define SS 64
#define HH 128
#define AA 8
#define CK 16
#define NCK (TT / CK)
#define VALO (BB * TT * AA)
#define HFIN (VALO + BB * TT)

#define LDW16(WV, P2, OFS) { float2 v_; \
    v_=(P2)[(OFS)+0];  WV[0] =pk2(v_.x,v_.y); v_=(P2)[(OFS)+1];  WV[1] =pk2(v_.x,v_.y); \
    v_=(P2)[(OFS)+2];  WV[2] =pk2(v_.x,v_.y); v_=(P2)[(OFS)+3];  WV[3] =pk2(v_.x,v_.y); \
    v_=(P2)[(OFS)+4];  WV[4] =pk2(v_.x,v_.y); v_=(P2)[(OFS)+5];  WV[5] =pk2(v_.x,v_.y); \
    v_=(P2)[(OFS)+6];  WV[6] =pk2(v_.x,v_.y); v_=(P2)[(OFS)+7];  WV[7] =pk2(v_.x,v_.y); \
    v_=(P2)[(OFS)+8];  WV[8] =pk2(v_.x,v_.y); v_=(P2)[(OFS)+9];  WV[9] =pk2(v_.x,v_.y); \
    v_=(P2)[(OFS)+10]; WV[10]=pk2(v_.x,v_.y); v_=(P2)[(OFS)+11]; WV[11]=pk2(v_.x,v_.y); \
    v_=(P2)[(OFS)+12]; WV[12]=pk2(v_.x,v_.y); v_=(P2)[(OFS)+13]; WV[13]=pk2(v_.x,v_.y); \
    v_=(P2)[(OFS)+14]; WV[14]=pk2(v_.x,v_.y); v_=(P2)[(OFS)+15]; WV[15]=pk2(v_.x,v_.y); }

// half-row (w0,w1 = 32 pairs) dot LDS half-vector at ph4 (8 float4) -> A0
#define HMVX(A0) { float4 u_; float c0_=0.f,c1_=0.f,c2_=0.f,c3_=0.f; \
  u_=ph4[0]; c0_=dot2a(f2h(w0[0]), f2h(u_.x),c0_); c0_=dot2a(f2h(w0[1]), f2h(u_.y),c0_); c0_=dot2a(f2h(w0[2]), f2h(u_.z),c0_); c0_=dot2a(f2h(w0[3]), f2h(u_.w),c0_); \
  u_=ph4[1]; c1_=dot2a(f2h(w0[4]), f2h(u_.x),c1_); c1_=dot2a(f2h(w0[5]), f2h(u_.y),c1_); c1_=dot2a(f2h(w0[6]), f2h(u_.z),c1_); c1_=dot2a(f2h(w0[7]), f2h(u_.w),c1_); \
  u_=ph4[2]; c2_=dot2a(f2h(w0[8]), f2h(u_.x),c2_); c2_=dot2a(f2h(w0[9]), f2h(u_.y),c2_); c2_=dot2a(f2h(w0[10]),f2h(u_.z),c2_); c2_=dot2a(f2h(w0[11]),f2h(u_.w),c2_); \
  u_=ph4[3]; c3_=dot2a(f2h(w0[12]),f2h(u_.x),c3_); c3_=dot2a(f2h(w0[13]),f2h(u_.y),c3_); c3_=dot2a(f2h(w0[14]),f2h(u_.z),c3_); c3_=dot2a(f2h(w0[15]),f2h(u_.w),c3_); \
  u_=ph4[4]; c0_=dot2a(f2h(w1[0]), f2h(u_.x),c0_); c0_=dot2a(f2h(w1[1]), f2h(u_.y),c0_); c0_=dot2a(f2h(w1[2]), f2h(u_.z),c0_); c0_=dot2a(f2h(w1[3]), f2h(u_.w),c0_); \
  u_=ph4[5]; c1_=dot2a(f2h(w1[4]), f2h(u_.x),c1_); c1_=dot2a(f2h(w1[5]), f2h(u_.y),c1_); c1_=dot2a(f2h(w1[6]), f2h(u_.z),c1_); c1_=dot2a(f2h(w1[7]), f2h(u_.w),c1_); \
  u_=ph4[6]; c2_=dot2a(f2h(w1[8]), f2h(u_.x),c2_); c2_=dot2a(f2h(w1[9]), f2h(u_.y),c2_); c2_=dot2a(f2h(w1[10]),f2h(u_.z),c2_); c2_=dot2a(f2h(w1[11]),f2h(u_.w),c2_); \
  u_=ph4[7]; c3_=dot2a(f2h(w1[12]),f2h(u_.x),c3_); c3_=dot2a(f2h(w1[13]),f2h(u_.y),c3_); c3_=dot2a(f2h(w1[14]),f2h(u_.z),c3_); c3_=dot2a(f2h(w1[15]),f2h(u_.w),c3_); \
  A0 = (c0_ + c1_) + (c2_ + c3_); }

#define FD4(WV, J, U) \
    f0=dot2a(f2h(WV[(J)+0]),f2h(U.x),f0); f1=dot2a(f2h(WV[(J)+1]),f2h(U.y),f1); \
    f0=dot2a(f2h(WV[(J)+2]),f2h(U.z),f0); f1=dot2a(f2h(WV[(J)+3]),f2h(U.w),f1);

// ======================= PHASE 1 =======================
// Block: (b, 128-t chunk). 8 rounds of 16 t; 4 barriers/round.
__global__ void __launch_bounds__(768, 2) p1_kernel(
    const float* __restrict__ x,   const float* __restrict__ Wf,
    const float* __restrict__ bfe, const float* __restrict__ gf,
    const float* __restrict__ btf, const float* __restrict__ Wih,
    const float* __restrict__ bih, unsigned short* __restrict__ gxws)
{
    const int tid = threadIdx.x;
    const int b  = blockIdx.x >> 2;
    const int t0 = (blockIdx.x & 3) * 128;

    __shared__ __align__(16) _Float16 xh2[128][SS];      // 16 KB
    __shared__ __align__(16) _Float16 zh[CK][HH];        // 4 KB
    __shared__ __align__(16) float fraw[CK][132];        // padded rows
    __shared__ float musd1[CK][2];
    __shared__ __align__(16) float gfl[HH], btfl[HH];

    const int l  = tid & 63;
    const int w  = tid >> 6;
    const int r  = (w << 5) | (l & 31);   // 0..383
    const int hf = (l >> 5) & 1;

    f16v w0, w1;   // half Wih row
    {
        const float2* p2 = (const float2*)(Wih + r * HH + hf * 64);
        LDW16(w0, p2, 0) LDW16(w1, p2, 16)
    }
    const float breg = bih[r];

    f16v fw0 = 0.f;
    float bfr = 0.f;
    if (tid < 256) {   // half Wf row (rows 0..127)
        const float2* q2 = (const float2*)(Wf + r * SS + hf * 32);
        LDW16(fw0, q2, 0)
        bfr = bfe[r];
    }
    if (tid < HH) { gfl[tid] = gf[tid]; btfl[tid] = btf[tid]; }

    {   // stage x chunk as fp16
        const float4* xb = (const float4*)(x + ((size_t)b * TT + t0) * SS);
        ushort4* xd = (ushort4*)&xh2[0][0];
        for (int idx = tid; idx < 2048; idx += 768) {
            float4 v = xb[idx];
            ushort4 p; p.x = hpk(v.x); p.y = hpk(v.y); p.z = hpk(v.z); p.w = hpk(v.w);
            xd[idx] = p;
        }
    }
    __syncthreads();

    for (int r8 = 0; r8 < 8; ++r8) {
        // SegA: features, 16 t (shfl chains pipeline across t)
        if (tid < 256) {
            #pragma unroll 4
            for (int tq = 0; tq < CK; ++tq) {
                const float4* px4 = ((const float4*)xh2[r8 * CK + tq]) + hf * 4;
                float f0 = 0.f, f1 = 0.f;
                float4 u_;
                u_ = px4[0]; FD4(fw0, 0, u_)
                u_ = px4[1]; FD4(fw0, 4, u_)
                u_ = px4[2]; FD4(fw0, 8, u_)
                u_ = px4[3]; FD4(fw0, 12, u_)
                float p = f0 + f1;
                p += __shfl_xor(p, 32);
                if (hf == 0) fraw[tq][r] = p + bfr;
            }
        }
        BAR();
        // SegB: LN stats, serial sums (no shfl)
        if (tid < 32) {
            int tq = tid >> 1, which = tid & 1;
            const float4* pf = (const float4*)fraw[tq];
            float s = 0.f;
            if (which == 0) {
                for (int k2 = 0; k2 < 32; ++k2) { float4 v = pf[k2]; s += (v.x + v.y) + (v.z + v.w); }
                musd1[tq][0] = s * (1.f / 128.f);
            } else {
                for (int k2 = 0; k2 < 32; ++k2) { float4 v = pf[k2]; s += (v.x*v.x + v.y*v.y) + (v.z*v.z + v.w*v.w); }
                musd1[tq][1] = s * (1.f / 128.f);
            }
        }
        BAR();
        // SegC: z = relu(LN(fraw))
        if (tid >= 256 && tid < 512) {
            int u = tid - 256;
            int tq = u >> 4, d = (u & 15) * 8;
            float mu = musd1[tq][0];
            float rstd = rsqrtf(musd1[tq][1] - mu * mu + 1e-5f);
            const float4* pf = (const float4*)&fraw[tq][d];
            const float4* pg = (const float4*)&gfl[d];
            const float4* pb = (const float4*)&btfl[d];
            float4 a0v = pf[0], a1v = pf[1], g0 = pg[0], g1 = pg[1], b0 = pb[0], b1 = pb[1];
            ushort4 o0, o1;
            o0.x = hpk(fmaxf((a0v.x - mu) * rstd * g0.x + b0.x, 0.f));
            o0.y = hpk(fmaxf((a0v.y - mu) * rstd * g0.y + b0.y, 0.f));
            o0.z = hpk(fmaxf((a0v.z - mu) * rstd * g0.z + b0.z, 0.f));
            o0.w = hpk(fmaxf((a0v.w - mu) * rstd * g0.w + b0.w, 0.f));
            o1.x = hpk(fmaxf((a1v.x - mu) * rstd * g1.x + b1.x, 0.f));
            o1.y = hpk(fmaxf((a1v.y - mu) * rstd * g1.y + b1.y, 0.f));
            o1.z = hpk(fmaxf((a1v.z - mu) * rstd * g1.z + b1.z, 0.f));
            o1.w = hpk(fmaxf((a1v.w - mu) * rstd * g1.w + b1.w, 0.f));
            ((ushort4*)&zh[tq][d])[0] = o0;
            ((ushort4*)&zh[tq][d])[1] = o1;
        }
        BAR();
        // SegD: gx matvec, 16 t, all 768 threads (half-rows)
        {
            #pragma unroll 4
            for (int tq = 0; tq < CK; ++tq) {
                const float4* ph4 = ((const float4*)zh[tq]) + hf * 8;
                float a0;
                HMVX(a0)
                a0 += __shfl_xor(a0, 32);
                if (hf == 0)
                    gxws[((size_t)b * TT + t0 + r8 * CK + tq) * 384 + r] = hpk(a0 + breg);
            }
        }
        BAR();
    }
}

// ======================= PHASE 2 =======================
__global__ void __launch_bounds__(768, 2) p2_kernel(
    const float* __restrict__ hx,  const int* __restrict__ done,
    const float* __restrict__ Whh, const float* __restrict__ bhh,
    const float* __restrict__ gr,  const float* __restrict__ btr,
    const float* __restrict__ Wp,  const float* __restrict__ bp,
    const float* __restrict__ Wv,  const float* __restrict__ bv,
    const unsigned short* __restrict__ gxws, float* __restrict__ out)
{
    const int tid = threadIdx.x;
    const int b   = blockIdx.x;

    __shared__ __align__(16) _Float16 hsh[HH];
    __shared__ __align__(16) float ghl[384];
    __shared__ __align__(16) _Float16 gxb[2][CK][384];   // 24 KB
    __shared__ __align__(16) float hnr[32][132];         // 16.9 KB, padded
    __shared__ __align__(16) float ylr[CK][132];         // 8.4 KB, padded
    __shared__ __align__(16) float wpl[9][132];          // padded
    __shared__ float bpl[9];
    __shared__ __align__(16) float grl[HH], btrl[HH];
    __shared__ float musd2[CK][2];
    __shared__ int dsh[TT];

    const int l  = tid & 63;
    const int w  = tid >> 6;
    const int r  = (w << 5) | (l & 31);
    const int hf = (l >> 5) & 1;

    f16v w0, w1;   // half Whh row
    {
        const float2* p2 = (const float2*)(Whh + r * HH + hf * 64);
        LDW16(w0, p2, 0) LDW16(w1, p2, 16)
    }
    const float breg = bhh[r];

    float hprev = 0.f;
    if (tid < HH) {
        hprev = hx[b * HH + tid];
        hsh[tid] = (_Float16)hprev;
        grl[tid] = gr[tid]; btrl[tid] = btr[tid];
    }
    for (int idx = tid; idx < 9 * HH; idx += 768) {
        int row = idx >> 7, col = idx & 127;
        wpl[row][col] = (row < 8) ? Wp[row * HH + col] : Wv[col];
    }
    if (tid < 9) bpl[tid] = (tid < 8) ? bp[tid] : bv[0];
    for (int idx = tid; idx < TT; idx += 768) dsh[idx] = done[b * TT + idx];

    const bool isStg = tid >= 512;
    const int  s = tid - 512;                // 0..255
    const unsigned short* base = gxws + (size_t)b * TT * 384;
    ushort4 r0, r1, r2, r3, r4, r5;
    if (isStg) {   // chunk 0
        const ushort4* cb0 = (const ushort4*)base;
        r0 = cb0[0*256+s]; r1 = cb0[1*256+s]; r2 = cb0[2*256+s];
        r3 = cb0[3*256+s]; r4 = cb0[4*256+s]; r5 = cb0[5*256+s];
        ushort4* gd = (ushort4*)&gxb[0][0][0];
        gd[0*256+s]=r0; gd[1*256+s]=r1; gd[2*256+s]=r2;
        gd[3*256+s]=r3; gd[4*256+s]=r4; gd[5*256+s]=r5;
    }
    __syncthreads();

    for (int c = 0; c < NCK; ++c) {
        const int cb = c & 1;
        if (isStg && c + 1 < NCK) {
            const ushort4* cbp = (const ushort4*)(base + (size_t)(c + 1) * CK * 384);
            r0 = cbp[0*256+s]; r1 = cbp[1*256+s]; r2 = cbp[2*256+s];
            r3 = cbp[3*256+s]; r4 = cbp[4*256+s]; r5 = cbp[5*256+s];
        }
        for (int j = 0; j < CK; ++j) {
            const int i = c * CK + j;
            // ---- SegA: gh matvec (all threads, half-rows) ----
            {
                const float4* ph4 = ((const float4*)hsh) + hf * 8;
                float a0;
                HMVX(a0)
                a0 += __shfl_xor(a0, 32);
                if (hf == 0) ghl[r] = a0 + breg;
            }
            BAR();
            // ---- SegB: gates (threads 0-127) + bulk bursts (512-767) ----
            if (tid < HH) {
                float xr_ = (float)gxb[cb][j][tid]       + ghl[tid];
                float xz_ = (float)gxb[cb][j][HH + tid]  + ghl[HH + tid];
                float xn_ = (float)gxb[cb][j][2*HH + tid];
                float hn_ = ghl[2*HH + tid];
                float r_ = 1.f / (1.f + __expf(-xr_));
                float u_ = 1.f / (1.f + __expf(-xz_));
                float a_ = xn_ + r_ * hn_;
                a_ = fminf(fmaxf(a_, -20.f), 20.f);
                float e2 = __expf(2.f * a_);
                float n_ = (e2 - 1.f) / (e2 + 1.f);
                float hn2 = (1.f - u_) * n_ + u_ * hprev;
                hnr[i & 31][tid] = hn2;
                float hm = hn2 * (dsh[i] ? 0.f : 1.f);
                hprev = hm;
                hsh[tid] = (_Float16)hm;
                if (i == TT - 1) out[HFIN + b * HH + tid] = hm;
            } else if (isStg && c >= 1) {
                if (j == 0 && s < CK) {            // stats for chunk c-1, t16 = s
                    int row = ((c - 1) * CK + s) & 31;
                    const float4* ph = (const float4*)hnr[row];
                    float sv = 0.f, qv = 0.f;
                    for (int k2 = 0; k2 < 32; ++k2) {
                        float4 v = ph[k2];
                        sv += (v.x + v.y) + (v.z + v.w);
                        qv += (v.x*v.x + v.y*v.y) + (v.z*v.z + v.w*v.w);
                    }
                    float mu = sv * (1.f / 128.f);
                    musd2[s][0] = mu;
                    musd2[s][1] = rsqrtf(qv * (1.f / 128.f) - mu * mu + 1e-5f);
                } else if (j == 1) {               // y for chunk c-1
                    int t16 = s >> 4, k = s & 15;
                    int row = ((c - 1) * CK + t16) & 31;
                    float mu = musd2[t16][0], rs = musd2[t16][1];
                    const float4* ph = (const float4*)&hnr[row][k * 8];
                    const float4* pg = (const float4*)&grl[k * 8];
                    const float4* pb = (const float4*)&btrl[k * 8];
                    float4 h0 = ph[0], h1 = ph[1], g0 = pg[0], g1 = pg[1], b0 = pb[0], b1 = pb[1];
                    float4 y0, y1;
                    y0.x = (h0.x - mu) * rs * g0.x + b0.x;
                    y0.y = (h0.y - mu) * rs * g0.y + b0.y;
                    y0.z = (h0.z - mu) * rs * g0.z + b0.z;
                    y0.w = (h0.w - mu) * rs * g0.w + b0.w;
                    y1.x = (h1.x - mu) * rs * g1.x + b1.x;
                    y1.y = (h1.y - mu) * rs * g1.y + b1.y;
                    y1.z = (h1.z - mu) * rs * g1.z + b1.z;
                    y1.w = (h1.w - mu) * rs * g1.w + b1.w;
                    ((float4*)&ylr[t16][k * 8])[0] = y0;
                    ((float4*)&ylr[t16][k * 8])[1] = y1;
                } else if (j == 2 && s < 144) {    // head dots, one output/thread
                    int t16 = s / 9, hd = s - t16 * 9;
                    const float4* py = (const float4*)ylr[t16];
                    const float4* pw = (const float4*)wpl[hd];
                    float acc = 0.f;
                    for (int k2 = 0; k2 < 32; ++k2) {
                        float4 yv = py[k2], wv = pw[k2];
                        acc += (yv.x*wv.x + yv.y*wv.y) + (yv.z*wv.z + yv.w*wv.w);
                    }
                    int t = (c - 1) * CK + t16;
                    float o = acc + bpl[hd];
                    if (hd < 8) out[((size_t)b * TT + t) * AA + hd] = o;
                    else        out[VALO + b * TT + t] = o;
                }
            }
            BAR();
        }
        if (isStg && c + 1 < NCK) {   // stage next chunk (16 steps of vmcnt slack)
            ushort4* gd = (ushort4*)&gxb[cb ^ 1][0][0];
            gd[0*256+s]=r0; gd[1*256+s]=r1; gd[2*256+s]=r2;
            gd[3*256+s]=r3; gd[4*256+s]=r4; gd[5*256+s]=r5;
        }
    }

    // ---- epilogue: LN+y+heads for the last chunk ----
    if (isStg && s < CK) {
        int row = ((NCK - 1) * CK + s) & 31;
        const float4* ph = (const float4*)hnr[row];
        float sv = 0.f, qv = 0.f;
        for (int k2 = 0; k2 < 32; ++k2) {
            float4 v = ph[k2];
            sv += (v.x + v.y) + (v.z + v.w);
            qv += (v.x*v.x + v.y*v.y) + (v.z*v.z + v.w*v.w);
        }
        float mu = sv * (1.f / 128.f);
        musd2[s][0] = mu;
        musd2[s][1] = rsqrtf(qv * (1.f / 128.f) - mu * mu + 1e-5f);
    }
    BAR();
    if (isStg) {
        int t16 = s >> 4, k = s & 15;
        int row = ((NCK - 1) * CK + t16) & 31;
        float mu = musd2[t16][0], rs = musd2[t16][1];
        const float4* ph = (const float4*)&hnr[row][k * 8];
        const float4* pg = (const float4*)&grl[k * 8];
        const float4* pb = (const float4*)&btrl[k * 8];
        float4 h0 = ph[0], h1 = ph[1], g0 = pg[0], g1 = pg[1], b0 = pb[0], b1 = pb[1];
        float4 y0, y1;
        y0.x = (h0.x - mu) * rs * g0.x + b0.x;
        y0.y = (h0.y - mu) * rs * g0.y + b0.y;
        y0.z = (h0.z - mu) * rs * g0.z + b0.z;
        y0.w = (h0.w - mu) * rs * g0.w + b0.w;
        y1.x = (h1.x - mu) * rs * g1.x + b1.x;
        y1.y = (h1.y - mu) * rs * g1.y + b1.y;
        y1.z = (h1.z - mu) * rs * g1.z + b1.z;
        y1.w = (h1.w - mu) * rs * g1.w + b1.w;
        ((float4*)&ylr[t16][k * 8])[0] = y0;
        ((float4*)&ylr[t16][k * 8])[1] = y1;
    }
    BAR();
    if (isStg && s < 144) {
        int t16 = s / 9, hd = s - t16 * 9;
        const float4* py = (const float4*)ylr[t16];
        const float4* pw = (const float4*)wpl[hd];
        float acc = 0.f;
        for (int k2 = 0; k2 < 32; ++k2) {
            float4 yv = py[k2], wv = pw[k2];
            acc += (yv.x*wv.x + yv.y*wv.y) + (yv.z*wv.z + yv.w*wv.w);
        }
        int t = (NCK - 1) * CK + t16;
        float o = acc + bpl[hd];
        if (hd < 8) out[((size_t)b * TT + t) * AA + hd] = o;
        else        out[VALO + b * TT + t] = o;
    }
}

extern "C" void kernel_launch(void* const* d_in, const int* in_sizes, int n_in,
                              void* d_out, int out_size, void* d_ws, size_t ws_size,
                              hipStream_t stream) {
    const float* x   = (const float*)d_in[0];
    const float* hx  = (const float*)d_in[1];
    const int*   dn  = (const int*)d_in[2];
    const float* Wf  = (const float*)d_in[3];
    const float* bfe = (const float*)d_in[4];
    const float* gf  = (const float*)d_in[5];
    const float* btf = (const float*)d_in[6];
    const float* Wih = (const float*)d_in[7];
    const float* Whh = (const float*)d_in[8];
    const float* bih = (const float*)d_in[9];
    const float* bhh = (const float*)d_in[10];
    const float* gr  = (const float*)d_in[11];
    const float* btr = (const float*)d_in[12];
    const float* Wp  = (const float*)d_in[13];
    const float* bp  = (const float*)d_in[14];
    const float* Wv  = (const float*)d_in[15];
    const float* bv  = (const float*)d_in[16];
    float* out = (float*)d_out;

    unsigned short* gxws = (unsigned short*)d_ws;   // 201.3 MB gx buffer (fits, R7/R8 ran this path)
    hipLaunchKernelGGL(p1_kernel, dim3(BB * 4), dim3(768), 0, stream,
                       x, Wf, bfe, gf, btf, Wih, bih, gxws);
    hipLaunchKernelGGL(p2_kernel, dim3(BB), dim3(768), 0, stream,
                       hx, dn, Whh, bhh, gr, btr, Wp, bp, Wv, bv, gxws, out);
}

// Round 10
// 1370.487 us; speedup vs baseline: 1.5959x; 1.1017x over previous
//
#include <hip/hip_runtime.h>

// RecurrentActorCritic B=512,T=512,S=64,H=128,A=8 (fp32 I/O).
// R9 post-mortem: p2 = 816us (2 barriers/chain-step @ ~300cyc each dominate;
// VALUBusy 39%); p1 = 694us (2048-block weight-gather prologue suspect).
// R10: p2 = 2 chains/block phase-offset (grid 256, 1 block/CU): interval A =
// matvec(chainA,i)+gates(chainB,i-1); interval B = matvec(B,i)+gates(A,i);
// ONE barrier per chain-step, gates always overlap the other chain's matvec.
// Weights shared across chains (Whh half-row, 32 VGPR). Bursts (LN/y/heads,
// zero cross-lane) at j==1/2/3 to avoid hnr row races. p1: 512 blocks
// (4x fewer prologues, single resident dispatch round), segments unchanged.

typedef _Float16 h2t __attribute__((ext_vector_type(2)));
typedef float f16v __attribute__((ext_vector_type(16)));

__device__ __forceinline__ float dot2a(h2t a, h2t b, float c) {
    return __builtin_amdgcn_fdot2(a, b, c, false);
}
__device__ __forceinline__ h2t f2h(float f) { return __builtin_bit_cast(h2t, f); }
__device__ __forceinline__ float pk2(float lo, float hi) {
    h2t a; a.x = (_Float16)lo; a.y = (_Float16)hi;
    return __builtin_bit_cast(float, a);
}
__device__ __forceinline__ unsigned short hpk(float v) {
    return __builtin_bit_cast(unsigned short, (_Float16)v);
}

// LDS-only barrier: drain ds ops, leave global loads/stores in flight.
#define BAR() __asm__ volatile("s_waitcnt lgkmcnt(0)\n\ts_barrier" ::: "memory")

#define BB 512
#define TT 512
#define SS 64
#define HH 128
#define AA 8
#define CK 16
#define NCK (TT / CK)
#define VALO (BB * TT * AA)
#define HFIN (VALO + BB * TT)

#define LDW16(WV, P2, OFS) { float2 v_; \
    v_=(P2)[(OFS)+0];  WV[0] =pk2(v_.x,v_.y); v_=(P2)[(OFS)+1];  WV[1] =pk2(v_.x,v_.y); \
    v_=(P2)[(OFS)+2];  WV[2] =pk2(v_.x,v_.y); v_=(P2)[(OFS)+3];  WV[3] =pk2(v_.x,v_.y); \
    v_=(P2)[(OFS)+4];  WV[4] =pk2(v_.x,v_.y); v_=(P2)[(OFS)+5];  WV[5] =pk2(v_.x,v_.y); \
    v_=(P2)[(OFS)+6];  WV[6] =pk2(v_.x,v_.y); v_=(P2)[(OFS)+7];  WV[7] =pk2(v_.x,v_.y); \
    v_=(P2)[(OFS)+8];  WV[8] =pk2(v_.x,v_.y); v_=(P2)[(OFS)+9];  WV[9] =pk2(v_.x,v_.y); \
    v_=(P2)[(OFS)+10]; WV[10]=pk2(v_.x,v_.y); v_=(P2)[(OFS)+11]; WV[11]=pk2(v_.x,v_.y); \
    v_=(P2)[(OFS)+12]; WV[12]=pk2(v_.x,v_.y); v_=(P2)[(OFS)+13]; WV[13]=pk2(v_.x,v_.y); \
    v_=(P2)[(OFS)+14]; WV[14]=pk2(v_.x,v_.y); v_=(P2)[(OFS)+15]; WV[15]=pk2(v_.x,v_.y); }

// half-row (w0,w1 = 32 pairs) dot LDS half-vector at ph4 (8 float4) -> A0
#define HMVX(A0) { float4 u_; float c0_=0.f,c1_=0.f,c2_=0.f,c3_=0.f; \
  u_=ph4[0]; c0_=dot2a(f2h(w0[0]), f2h(u_.x),c0_); c0_=dot2a(f2h(w0[1]), f2h(u_.y),c0_); c0_=dot2a(f2h(w0[2]), f2h(u_.z),c0_); c0_=dot2a(f2h(w0[3]), f2h(u_.w),c0_); \
  u_=ph4[1]; c1_=dot2a(f2h(w0[4]), f2h(u_.x),c1_); c1_=dot2a(f2h(w0[5]), f2h(u_.y),c1_); c1_=dot2a(f2h(w0[6]), f2h(u_.z),c1_); c1_=dot2a(f2h(w0[7]), f2h(u_.w),c1_); \
  u_=ph4[2]; c2_=dot2a(f2h(w0[8]), f2h(u_.x),c2_); c2_=dot2a(f2h(w0[9]), f2h(u_.y),c2_); c2_=dot2a(f2h(w0[10]),f2h(u_.z),c2_); c2_=dot2a(f2h(w0[11]),f2h(u_.w),c2_); \
  u_=ph4[3]; c3_=dot2a(f2h(w0[12]),f2h(u_.x),c3_); c3_=dot2a(f2h(w0[13]),f2h(u_.y),c3_); c3_=dot2a(f2h(w0[14]),f2h(u_.z),c3_); c3_=dot2a(f2h(w0[15]),f2h(u_.w),c3_); \
  u_=ph4[4]; c0_=dot2a(f2h(w1[0]), f2h(u_.x),c0_); c0_=dot2a(f2h(w1[1]), f2h(u_.y),c0_); c0_=dot2a(f2h(w1[2]), f2h(u_.z),c0_); c0_=dot2a(f2h(w1[3]), f2h(u_.w),c0_); \
  u_=ph4[5]; c1_=dot2a(f2h(w1[4]), f2h(u_.x),c1_); c1_=dot2a(f2h(w1[5]), f2h(u_.y),c1_); c1_=dot2a(f2h(w1[6]), f2h(u_.z),c1_); c1_=dot2a(f2h(w1[7]), f2h(u_.w),c1_); \
  u_=ph4[6]; c2_=dot2a(f2h(w1[8]), f2h(u_.x),c2_); c2_=dot2a(f2h(w1[9]), f2h(u_.y),c2_); c2_=dot2a(f2h(w1[10]),f2h(u_.z),c2_); c2_=dot2a(f2h(w1[11]),f2h(u_.w),c2_); \
  u_=ph4[7]; c3_=dot2a(f2h(w1[12]),f2h(u_.x),c3_); c3_=dot2a(f2h(w1[13]),f2h(u_.y),c3_); c3_=dot2a(f2h(w1[14]),f2h(u_.z),c3_); c3_=dot2a(f2h(w1[15]),f2h(u_.w),c3_); \
  A0 = (c0_ + c1_) + (c2_ + c3_); }

#define FD4(WV, J, U) \
    f0=dot2a(f2h(WV[(J)+0]),f2h(U.x),f0); f1=dot2a(f2h(WV[(J)+1]),f2h(U.y),f1); \
    f0=dot2a(f2h(WV[(J)+2]),f2h(U.z),f0); f1=dot2a(f2h(WV[(J)+3]),f2h(U.w),f1);

// ======================= PHASE 1 =======================
// 512 blocks (one b each), 4 internal 128-t chunks, 8 rounds of 16 t each.
__global__ void __launch_bounds__(768, 2) p1_kernel(
    const float* __restrict__ x,   const float* __restrict__ Wf,
    const float* __restrict__ bfe, const float* __restrict__ gf,
    const float* __restrict__ btf, const float* __restrict__ Wih,
    const float* __restrict__ bih, unsigned short* __restrict__ gxws)
{
    const int tid = threadIdx.x;
    const int b   = blockIdx.x;

    __shared__ __align__(16) _Float16 xh2[128][SS];
    __shared__ __align__(16) _Float16 zh[CK][HH];
    __shared__ __align__(16) float fraw[CK][132];
    __shared__ float musd1[CK][2];
    __shared__ __align__(16) float gfl[HH], btfl[HH];

    const int l  = tid & 63;
    const int w  = tid >> 6;
    const int r  = (w << 5) | (l & 31);
    const int hf = (l >> 5) & 1;

    f16v w0, w1;   // half Wih row
    {
        const float2* p2 = (const float2*)(Wih + r * HH + hf * 64);
        LDW16(w0, p2, 0) LDW16(w1, p2, 16)
    }
    const float breg = bih[r];

    f16v fw0 = 0.f;
    float bfr = 0.f;
    if (tid < 256) {   // half Wf row (rows 0..127)
        const float2* q2 = (const float2*)(Wf + r * SS + hf * 32);
        LDW16(fw0, q2, 0)
        bfr = bfe[r];
    }
    if (tid < HH) { gfl[tid] = gf[tid]; btfl[tid] = btf[tid]; }

    for (int ch = 0; ch < 4; ++ch) {
        {   // stage x chunk as fp16
            const float4* xb = (const float4*)(x + ((size_t)b * TT + ch * 128) * SS);
            ushort4* xd = (ushort4*)&xh2[0][0];
            for (int idx = tid; idx < 2048; idx += 768) {
                float4 v = xb[idx];
                ushort4 p; p.x = hpk(v.x); p.y = hpk(v.y); p.z = hpk(v.z); p.w = hpk(v.w);
                xd[idx] = p;
            }
        }
        __syncthreads();

        for (int r8 = 0; r8 < 8; ++r8) {
            // SegA: features, 16 t
            if (tid < 256) {
                #pragma unroll 4
                for (int tq = 0; tq < CK; ++tq) {
                    const float4* px4 = ((const float4*)xh2[r8 * CK + tq]) + hf * 4;
                    float f0 = 0.f, f1 = 0.f;
                    float4 u_;
                    u_ = px4[0]; FD4(fw0, 0, u_)
                    u_ = px4[1]; FD4(fw0, 4, u_)
                    u_ = px4[2]; FD4(fw0, 8, u_)
                    u_ = px4[3]; FD4(fw0, 12, u_)
                    float p = f0 + f1;
                    p += __shfl_xor(p, 32);
                    if (hf == 0) fraw[tq][r] = p + bfr;
                }
            }
            BAR();
            // SegB: LN stats, serial sums
            if (tid < 32) {
                int tq = tid >> 1, which = tid & 1;
                const float4* pf = (const float4*)fraw[tq];
                float s = 0.f;
                if (which == 0) {
                    for (int k2 = 0; k2 < 32; ++k2) { float4 v = pf[k2]; s += (v.x + v.y) + (v.z + v.w); }
                    musd1[tq][0] = s * (1.f / 128.f);
                } else {
                    for (int k2 = 0; k2 < 32; ++k2) { float4 v = pf[k2]; s += (v.x*v.x + v.y*v.y) + (v.z*v.z + v.w*v.w); }
                    musd1[tq][1] = s * (1.f / 128.f);
                }
            }
            BAR();
            // SegC: z = relu(LN(fraw))
            if (tid >= 256 && tid < 512) {
                int u = tid - 256;
                int tq = u >> 4, d = (u & 15) * 8;
                float mu = musd1[tq][0];
                float rstd = rsqrtf(musd1[tq][1] - mu * mu + 1e-5f);
                const float4* pf = (const float4*)&fraw[tq][d];
                const float4* pg = (const float4*)&gfl[d];
                const float4* pb = (const float4*)&btfl[d];
                float4 a0v = pf[0], a1v = pf[1], g0 = pg[0], g1 = pg[1], b0 = pb[0], b1 = pb[1];
                ushort4 o0, o1;
                o0.x = hpk(fmaxf((a0v.x - mu) * rstd * g0.x + b0.x, 0.f));
                o0.y = hpk(fmaxf((a0v.y - mu) * rstd * g0.y + b0.y, 0.f));
                o0.z = hpk(fmaxf((a0v.z - mu) * rstd * g0.z + b0.z, 0.f));
                o0.w = hpk(fmaxf((a0v.w - mu) * rstd * g0.w + b0.w, 0.f));
                o1.x = hpk(fmaxf((a1v.x - mu) * rstd * g1.x + b1.x, 0.f));
                o1.y = hpk(fmaxf((a1v.y - mu) * rstd * g1.y + b1.y, 0.f));
                o1.z = hpk(fmaxf((a1v.z - mu) * rstd * g1.z + b1.z, 0.f));
                o1.w = hpk(fmaxf((a1v.w - mu) * rstd * g1.w + b1.w, 0.f));
                ((ushort4*)&zh[tq][d])[0] = o0;
                ((ushort4*)&zh[tq][d])[1] = o1;
            }
            BAR();
            // SegD: gx matvec, 16 t, all 768 threads
            {
                #pragma unroll 4
                for (int tq = 0; tq < CK; ++tq) {
                    const float4* ph4 = ((const float4*)zh[tq]) + hf * 8;
                    float a0;
                    HMVX(a0)
                    a0 += __shfl_xor(a0, 32);
                    if (hf == 0)
                        gxws[((size_t)b * TT + ch * 128 + r8 * CK + tq) * 384 + r] = hpk(a0 + breg);
                }
            }
            BAR();
        }
    }
}

// ======================= PHASE 2 =======================
// 256 blocks, 2 chains each (bA=2*blk, bB=2*blk+1), phase-offset intervals.
__global__ void __launch_bounds__(768, 2) p2_kernel(
    const float* __restrict__ hx,  const int* __restrict__ done,
    const float* __restrict__ Whh, const float* __restrict__ bhh,
    const float* __restrict__ gr,  const float* __restrict__ btr,
    const float* __restrict__ Wp,  const float* __restrict__ bp,
    const float* __restrict__ Wv,  const float* __restrict__ bv,
    const unsigned short* __restrict__ gxws, float* __restrict__ out)
{
    const int tid = threadIdx.x;
    const int blk = blockIdx.x;

    __shared__ __align__(16) _Float16 hsh[2][HH];
    __shared__ __align__(16) float ghl[2][384];
    __shared__ __align__(16) _Float16 gxb[2][2][CK][384];   // 48 KB
    __shared__ __align__(16) float hnr[2][32][132];          // 33.8 KB
    __shared__ __align__(16) float ylr[2][CK][132];          // 16.9 KB
    __shared__ __align__(16) float wpl[9][132];
    __shared__ float bpl[9];
    __shared__ __align__(16) float grl[HH], btrl[HH];
    __shared__ float musd[2][CK][2];
    __shared__ int dsh[2][TT];

    const int l  = tid & 63;
    const int w  = tid >> 6;
    const int r  = (w << 5) | (l & 31);
    const int hf = (l >> 5) & 1;

    f16v w0, w1;   // half Whh row (shared by both chains)
    {
        const float2* p2 = (const float2*)(Whh + r * HH + hf * 64);
        LDW16(w0, p2, 0) LDW16(w1, p2, 16)
    }
    const float breg = bhh[r];

    float hprevA = 0.f, hprevB = 0.f;
    if (tid < HH) {
        hprevA = hx[(2 * blk + 0) * HH + tid];
        hprevB = hx[(2 * blk + 1) * HH + tid];
        hsh[0][tid] = (_Float16)hprevA;
        hsh[1][tid] = (_Float16)hprevB;
        grl[tid] = gr[tid]; btrl[tid] = btr[tid];
    }
    for (int idx = tid; idx < 9 * HH; idx += 768) {
        int row = idx >> 7, col = idx & 127;
        wpl[row][col] = (row < 8) ? Wp[row * HH + col] : Wv[col];
    }
    if (tid < 9) bpl[tid] = (tid < 8) ? bp[tid] : bv[0];
    for (int idx = tid; idx < 2 * TT; idx += 768)
        dsh[idx >> 9][idx & 511] = done[(2 * blk + (idx >> 9)) * TT + (idx & 511)];

    // gx staging: threads 128-383 (256), 6 ushort4 per chain per chunk
    const bool isStg = (tid >= 128) && (tid < 384);
    const int  sSt = tid - 128;
    const unsigned short* baseA = gxws + (size_t)(2 * blk + 0) * TT * 384;
    const unsigned short* baseB = gxws + (size_t)(2 * blk + 1) * TT * 384;
    ushort4 rA0, rA1, rA2, rA3, rA4, rA5, rB0, rB1, rB2, rB3, rB4, rB5;
    if (isStg) {   // chunk 0 -> buffer 0
        const ushort4* ca = (const ushort4*)baseA;
        const ushort4* cbp = (const ushort4*)baseB;
        rA0=ca[0*256+sSt]; rA1=ca[1*256+sSt]; rA2=ca[2*256+sSt];
        rA3=ca[3*256+sSt]; rA4=ca[4*256+sSt]; rA5=ca[5*256+sSt];
        rB0=cbp[0*256+sSt]; rB1=cbp[1*256+sSt]; rB2=cbp[2*256+sSt];
        rB3=cbp[3*256+sSt]; rB4=cbp[4*256+sSt]; rB5=cbp[5*256+sSt];
        ushort4* ga = (ushort4*)&gxb[0][0][0][0];
        ushort4* gb = (ushort4*)&gxb[1][0][0][0];
        ga[0*256+sSt]=rA0; ga[1*256+sSt]=rA1; ga[2*256+sSt]=rA2;
        ga[3*256+sSt]=rA3; ga[4*256+sSt]=rA4; ga[5*256+sSt]=rA5;
        gb[0*256+sSt]=rB0; gb[1*256+sSt]=rB1; gb[2*256+sSt]=rB2;
        gb[3*256+sSt]=rB3; gb[4*256+sSt]=rB4; gb[5*256+sSt]=rB5;
    }
    __syncthreads();

    const int s2 = tid - 512;   // burst lane (tid >= 512)

    // ---- gate step (tid < 128, d = tid) ----
    #define GATES(Y, T, HPREV) { \
        int d_ = tid; int sb_ = ((T) >> 4) & 1, sj_ = (T) & 15; \
        const _Float16* gxv = gxb[Y][sb_][sj_]; \
        const float* gy = ghl[Y]; \
        float xr_ = (float)gxv[d_] + gy[d_]; \
        float xz_ = (float)gxv[128 + d_] + gy[128 + d_]; \
        float xn_ = (float)gxv[256 + d_]; \
        float hn_ = gy[256 + d_]; \
        float r_ = 1.f / (1.f + __expf(-xr_)); \
        float u_ = 1.f / (1.f + __expf(-xz_)); \
        float a_ = xn_ + r_ * hn_; \
        a_ = fminf(fmaxf(a_, -20.f), 20.f); \
        float e2_ = __expf(2.f * a_); \
        float n_ = (e2_ - 1.f) / (e2_ + 1.f); \
        float hn2_ = (1.f - u_) * n_ + u_ * HPREV; \
        hnr[Y][(T) & 31][d_] = hn2_; \
        float hm_ = hn2_ * (dsh[Y][T] ? 0.f : 1.f); \
        HPREV = hm_; \
        hsh[Y][d_] = (_Float16)hm_; \
        if ((T) == TT - 1) out[HFIN + (2 * blk + (Y)) * HH + d_] = hm_; }

    // ---- bursts for chain Y, chunk cm1 (zero cross-lane) ----
    #define BSTAT(Y, CM1, SL) { \
        int row_ = (((CM1) * CK + (SL)) & 31); \
        const float4* ph_ = (const float4*)hnr[Y][row_]; \
        float sv_ = 0.f, qv_ = 0.f; \
        for (int k2 = 0; k2 < 32; ++k2) { float4 v_ = ph_[k2]; \
            sv_ += (v_.x + v_.y) + (v_.z + v_.w); \
            qv_ += (v_.x*v_.x + v_.y*v_.y) + (v_.z*v_.z + v_.w*v_.w); } \
        float mu_ = sv_ * (1.f / 128.f); \
        musd[Y][SL][0] = mu_; \
        musd[Y][SL][1] = rsqrtf(qv_ * (1.f / 128.f) - mu_ * mu_ + 1e-5f); }

    #define BY(Y, CM1, SL) { \
        int t16_ = (SL) >> 4, k_ = (SL) & 15; \
        int row_ = (((CM1) * CK + t16_) & 31); \
        float mu_ = musd[Y][t16_][0], rs_ = musd[Y][t16_][1]; \
        const float4* ph_ = (const float4*)&hnr[Y][row_][k_ * 8]; \
        const float4* pg_ = (const float4*)&grl[k_ * 8]; \
        const float4* pb_ = (const float4*)&btrl[k_ * 8]; \
        float4 h0_ = ph_[0], h1_ = ph_[1], g0_ = pg_[0], g1_ = pg_[1], b0_ = pb_[0], b1_ = pb_[1]; \
        float4 y0_, y1_; \
        y0_.x = (h0_.x - mu_) * rs_ * g0_.x + b0_.x; \
        y0_.y = (h0_.y - mu_) * rs_ * g0_.y + b0_.y; \
        y0_.z = (h0_.z - mu_) * rs_ * g0_.z + b0_.z; \
        y0_.w = (h0_.w - mu_) * rs_ * g0_.w + b0_.w; \
        y1_.x = (h1_.x - mu_) * rs_ * g1_.x + b1_.x; \
        y1_.y = (h1_.y - mu_) * rs_ * g1_.y + b1_.y; \
        y1_.z = (h1_.z - mu_) * rs_ * g1_.z + b1_.z; \
        y1_.w = (h1_.w - mu_) * rs_ * g1_.w + b1_.w; \
        ((float4*)&ylr[Y][t16_][k_ * 8])[0] = y0_; \
        ((float4*)&ylr[Y][t16_][k_ * 8])[1] = y1_; }

    #define BHEAD(Y, CM1, SL) { \
        int t16_ = (SL) / 9, hd_ = (SL) - t16_ * 9; \
        const float4* py_ = (const float4*)ylr[Y][t16_]; \
        const float4* pw_ = (const float4*)wpl[hd_]; \
        float acc_ = 0.f; \
        for (int k2 = 0; k2 < 32; ++k2) { float4 yv_ = py_[k2], wv_ = pw_[k2]; \
            acc_ += (yv_.x*wv_.x + yv_.y*wv_.y) + (yv_.z*wv_.z + yv_.w*wv_.w); } \
        int t_ = (CM1) * CK + t16_; \
        float o_ = acc_ + bpl[hd_]; \
        if (hd_ < 8) out[((size_t)(2 * blk + (Y)) * TT + t_) * AA + hd_] = o_; \
        else         out[VALO + (2 * blk + (Y)) * TT + t_] = o_; }

    #define MV(Y) { \
        const float4* ph4 = ((const float4*)hsh[Y]) + hf * 8; \
        float a0; HMVX(a0) \
        a0 += __shfl_xor(a0, 32); \
        if (hf == 0) ghl[Y][r] = a0 + breg; }

    for (int c = 0; c < NCK; ++c) {
        if (isStg && c + 1 < NCK) {   // issue next-chunk loads (16-step slack)
            const ushort4* ca = (const ushort4*)(baseA + (size_t)(c + 1) * CK * 384);
            const ushort4* cbp = (const ushort4*)(baseB + (size_t)(c + 1) * CK * 384);
            rA0=ca[0*256+sSt]; rA1=ca[1*256+sSt]; rA2=ca[2*256+sSt];
            rA3=ca[3*256+sSt]; rA4=ca[4*256+sSt]; rA5=ca[5*256+sSt];
            rB0=cbp[0*256+sSt]; rB1=cbp[1*256+sSt]; rB2=cbp[2*256+sSt];
            rB3=cbp[3*256+sSt]; rB4=cbp[4*256+sSt]; rB5=cbp[5*256+sSt];
        }
        for (int j = 0; j < CK; ++j) {
            const int i = c * CK + j;
            // ===== interval alpha: mv_A(i) + gates_B(i-1) + B-bursts =====
            MV(0)
            if (tid < HH && i >= 1) GATES(1, i - 1, hprevB)
            if (tid >= 512 && c >= 1) {
                if (j == 1 && s2 < CK)       BSTAT(1, c - 1, s2)
                else if (j == 2)             BY(1, c - 1, s2)
                else if (j == 3 && s2 < 144) BHEAD(1, c - 1, s2)
            }
            BAR();
            // ===== interval beta: mv_B(i) + gates_A(i) + A-bursts =====
            MV(1)
            if (tid < HH) GATES(0, i, hprevA)
            if (tid >= 512 && c >= 1) {
                if (j == 1 && s2 < CK)       BSTAT(0, c - 1, s2)
                else if (j == 2)             BY(0, c - 1, s2)
                else if (j == 3 && s2 < 144) BHEAD(0, c - 1, s2)
            }
            BAR();
        }
        if (isStg && c + 1 < NCK) {   // write staged regs into buffer (c+1)&1
            const int nb = (c + 1) & 1;
            ushort4* ga = (ushort4*)&gxb[0][nb][0][0];
            ushort4* gb = (ushort4*)&gxb[1][nb][0][0];
            ga[0*256+sSt]=rA0; ga[1*256+sSt]=rA1; ga[2*256+sSt]=rA2;
            ga[3*256+sSt]=rA3; ga[4*256+sSt]=rA4; ga[5*256+sSt]=rA5;
            gb[0*256+sSt]=rB0; gb[1*256+sSt]=rB1; gb[2*256+sSt]=rB2;
            gb[3*256+sSt]=rB3; gb[4*256+sSt]=rB4; gb[5*256+sSt]=rB5;
        }
    }

    // ===== epilogue =====
    if (tid < HH) GATES(1, TT - 1, hprevB)   // gates_B(511)
    BAR();
    if (tid >= 512) {                         // stats chunk 31, both chains
        if (s2 < CK)                    BSTAT(0, NCK - 1, s2)
        else if (s2 < 2 * CK)           BSTAT(1, NCK - 1, s2 - CK)
    }
    BAR();
    if (tid >= 512) BY(0, NCK - 1, s2)
    if (tid >= 256 && tid < 512) { int s3 = tid - 256; BY(1, NCK - 1, s3) }
    BAR();
    if (tid >= 512 && s2 < 144) BHEAD(0, NCK - 1, s2)
    if (tid >= 256 && tid < 400) { int s3 = tid - 256; BHEAD(1, NCK - 1, s3) }
}

extern "C" void kernel_launch(void* const* d_in, const int* in_sizes, int n_in,
                              void* d_out, int out_size, void* d_ws, size_t ws_size,
                              hipStream_t stream) {
    const float* x   = (const float*)d_in[0];
    const float* hx  = (const float*)d_in[1];
    const int*   dn  = (const int*)d_in[2];
    const float* Wf  = (const float*)d_in[3];
    const float* bfe = (const float*)d_in[4];
    const float* gf  = (const float*)d_in[5];
    const float* btf = (const float*)d_in[6];
    const float* Wih = (const float*)d_in[7];
    const float* Whh = (const float*)d_in[8];
    const float* bih = (const float*)d_in[9];
    const float* bhh = (const float*)d_in[10];
    const float* gr  = (const float*)d_in[11];
    const float* btr = (const float*)d_in[12];
    const float* Wp  = (const float*)d_in[13];
    const float* bp  = (const float*)d_in[14];
    const float* Wv  = (const float*)d_in[15];
    const float* bv  = (const float*)d_in[16];
    float* out = (float*)d_out;

    unsigned short* gxws = (unsigned short*)d_ws;   // 201.3 MB gx buffer
    hipLaunchKernelGGL(p1_kernel, dim3(BB), dim3(768), 0, stream,
                       x, Wf, bfe, gf, btf, Wih, bih, gxws);
    hipLaunchKernelGGL(p2_kernel, dim3(BB / 2), dim3(768), 0, stream,
                       hx, dn, Whh, bhh, gr, btr, Wp, bp, Wv, bv, gxws, out);
}